// Round 2
// baseline (615.971 us; speedup 1.0000x reference)
//
#include <hip/hip_runtime.h>
#include <hip/hip_bf16.h>
#include <stdint.h>

#define B_   8
#define S_   1042
#define H_   768
#define NH_  12
#define HD_  64
#define MLP_ 2048
#define T_   (B_*S_)    // 8336 tokens
#define MP_  8448       // tokens padded to 66*128
#define SP_  1088       // seq padded to 17*64
#define EPS_ 1e-6f

typedef __attribute__((ext_vector_type(8))) short bf16x8v;
typedef __attribute__((ext_vector_type(4))) float f32x4;
typedef __hip_bfloat16 bf16;

typedef __attribute__((address_space(1))) const void gas_void;
typedef __attribute__((address_space(3))) void las_void;

__device__ inline void gload_lds16(const void* g, void* l) {
  __builtin_amdgcn_global_load_lds((gas_void*)g, (las_void*)l, 16, 0, 0);
}

__device__ inline uint32_t packbf(float lo, float hi) {
  bf16 a = __float2bfloat16(lo), b = __float2bfloat16(hi);
  uint16_t ua = *reinterpret_cast<uint16_t*>(&a), ub = *reinterpret_cast<uint16_t*>(&b);
  return (uint32_t)ua | ((uint32_t)ub << 16);
}

// ---------------- zero fill ----------------
__global__ void fillz(uint4* p, long n16) {
  long i = (long)blockIdx.x * blockDim.x + threadIdx.x;
  long stride = (long)gridDim.x * blockDim.x;
  uint4 z; z.x = z.y = z.z = z.w = 0u;
  for (; i < n16; i += stride) p[i] = z;
}

// ---------------- weight convert + transpose (LDS-tiled): out[n*K+k] = W[k*N+n] ----------------
__global__ __launch_bounds__(256) void wcvt_t(const float* __restrict__ W, bf16* __restrict__ o,
                                              int K, int N) {
  __shared__ float tile[32][33];
  int kt = blockIdx.x, nt = blockIdx.y;
  int t = threadIdx.x;
  int r = t >> 5, c = t & 31;
#pragma unroll
  for (int i = 0; i < 4; i++)
    tile[i * 8 + r][c] = W[(long)(kt * 32 + i * 8 + r) * N + nt * 32 + c];
  __syncthreads();
#pragma unroll
  for (int i = 0; i < 4; i++)
    o[(long)(nt * 32 + i * 8 + r) * K + kt * 32 + c] = __float2bfloat16(tile[c][i * 8 + r]);
}

// ---------------- V transpose: qkv v-part -> vtf[(bh*64+d)*SP_+s] ----------------
__global__ __launch_bounds__(256) void vtran(const bf16* __restrict__ qkv, bf16* __restrict__ vtf) {
  __shared__ bf16 tile[32][66];
  int st = blockIdx.x, bh = blockIdx.y;
  int bb = bh / NH_, h = bh - bb * NH_;
  int s0 = st * 32;
  int t = threadIdx.x;
  int si = t >> 6, d = t & 63;
#pragma unroll
  for (int i = 0; i < 8; i++) {
    int s = s0 + i * 4 + si;
    bf16 v = __float2bfloat16(0.f);
    if (s < S_) v = qkv[(long)(bb * S_ + s) * 2304 + 1536 + h * 64 + d];
    tile[i * 4 + si][d] = v;
  }
  __syncthreads();
  int dd = t >> 5, sj = t & 31;
#pragma unroll
  for (int i = 0; i < 8; i++) {
    int d2 = i * 8 + dd;
    vtf[((long)bh * 64 + d2) * SP_ + s0 + sj] = tile[sj][d2];
  }
}

// ---------------- rmsnorm (768 wide), fp32 in -> bf16 out, zero pad rows ----------------
__global__ __launch_bounds__(256) void rmsnorm_k(const float* __restrict__ x,
                                                 const float* __restrict__ w,
                                                 bf16* __restrict__ o, int Mreal) {
  int row = blockIdx.x;
  bf16* orow = o + (long)row * H_;
  int t = threadIdx.x;
  if (row >= Mreal) {
    for (int i = t; i < H_; i += 256) orow[i] = __float2bfloat16(0.f);
    return;
  }
  const float* xr = x + (long)row * H_;
  float v0 = xr[t], v1 = xr[t + 256], v2 = xr[t + 512];
  float s = v0 * v0 + v1 * v1 + v2 * v2;
  for (int off = 32; off; off >>= 1) s += __shfl_down(s, off);
  __shared__ float red[4];
  if ((t & 63) == 0) red[t >> 6] = s;
  __syncthreads();
  float tot = red[0] + red[1] + red[2] + red[3];
  float inv = rsqrtf(tot * (1.f / H_) + EPS_);
  orow[t]       = __float2bfloat16(v0 * inv * w[t]);
  orow[t + 256] = __float2bfloat16(v1 * inv * w[t + 256]);
  orow[t + 512] = __float2bfloat16(v2 * inv * w[t + 512]);
}

// ---------------- bf16 GEMM: A (M x K, row-major) * Bt (N x K, row-major) ----------------
template <int EPI>
__global__ __launch_bounds__(256) void gemm_bf16(
    const bf16* __restrict__ A, const bf16* __restrict__ Bt, void* __restrict__ Out,
    const float* __restrict__ resid, const float* __restrict__ scale,
    int N, int K, int Mreal) {
  __shared__ __align__(16) bf16 As[128 * 32];
  __shared__ __align__(16) bf16 Bs[128 * 32];
  int tid = threadIdx.x;
  int lane = tid & 63, wid = tid >> 6;
  int wm = wid >> 1, wn = wid & 1;
  int lr = lane & 15, lg = lane >> 4;
  long rowA0 = (long)blockIdx.y * 128;
  long rowB0 = (long)blockIdx.x * 128;
  f32x4 z; z[0] = z[1] = z[2] = z[3] = 0.f;
  f32x4 acc[4][4];
#pragma unroll
  for (int mi = 0; mi < 4; mi++)
#pragma unroll
    for (int ni = 0; ni < 4; ni++) acc[mi][ni] = z;

  const int flat0 = wid * 512 + lane * 8;
  const bf16* Ab = A + rowA0 * K;
  const bf16* Bb = Bt + rowB0 * K;

  for (int k0 = 0; k0 < K; k0 += 32) {
    __syncthreads();
#pragma unroll
    for (int j = 0; j < 2; j++) {
      int flat = flat0 + j * 2048;
      int r = flat >> 5, c = flat & 31;
      gload_lds16(Ab + (long)r * K + k0 + c, &As[flat]);
      gload_lds16(Bb + (long)r * K + k0 + c, &Bs[flat]);
    }
    __syncthreads();
    bf16x8v af[4], bfr[4];
#pragma unroll
    for (int mi = 0; mi < 4; mi++)
      af[mi] = *(const bf16x8v*)&As[(wm * 64 + mi * 16 + lr) * 32 + lg * 8];
#pragma unroll
    for (int ni = 0; ni < 4; ni++)
      bfr[ni] = *(const bf16x8v*)&Bs[(wn * 64 + ni * 16 + lr) * 32 + lg * 8];
#pragma unroll
    for (int mi = 0; mi < 4; mi++)
#pragma unroll
      for (int ni = 0; ni < 4; ni++)
        acc[mi][ni] = __builtin_amdgcn_mfma_f32_16x16x32_bf16(af[mi], bfr[ni], acc[mi][ni], 0, 0, 0);
  }

#pragma unroll
  for (int mi = 0; mi < 4; mi++) {
#pragma unroll
    for (int ni = 0; ni < 4; ni++) {
#pragma unroll
      for (int r = 0; r < 4; r++) {
        long row = rowA0 + wm * 64 + mi * 16 + lg * 4 + r;
        long col = rowB0 + wn * 64 + ni * 16 + lr;
        float v = acc[mi][ni][r];
        if (EPI == 0) {
          ((bf16*)Out)[row * N + col] = __float2bfloat16(v);
        } else {
          if (row < Mreal)
            ((float*)Out)[row * N + col] = resid[row * N + col] + v * scale[col];
        }
      }
    }
  }
}

// ---------------- qk rmsnorm + rope + scale ----------------
__global__ __launch_bounds__(768) void qkv_post(
    const bf16* __restrict__ qkv, const float* __restrict__ qw, const float* __restrict__ kw,
    const float* __restrict__ cosT, const float* __restrict__ sinT,
    bf16* __restrict__ qf, bf16* __restrict__ kf) {
  int tok = blockIdx.x;
  int bb = tok / S_, s = tok - bb * S_;
  int h = threadIdx.x >> 6, d = threadIdx.x & 63;
  const bf16* base = qkv + (long)tok * 2304 + h * 64 + d;
  float q = __bfloat162float(base[0]);
  float k = __bfloat162float(base[768]);
  float qs = q * q, ks = k * k;
  for (int off = 32; off; off >>= 1) {
    qs += __shfl_xor(qs, off);
    ks += __shfl_xor(ks, off);
  }
  q *= rsqrtf(qs * (1.f / 64.f) + EPS_) * qw[d];
  k *= rsqrtf(ks * (1.f / 64.f) + EPS_) * kw[d];
  if (s >= S_ - 1024) {
    int pos = s - (S_ - 1024);
    int i = d >> 1;
    float c = cosT[pos * 32 + i], sn = sinT[pos * 32 + i];
    float qp = __shfl_xor(q, 1), kp = __shfl_xor(k, 1);
    if (d & 1) { q = qp * sn + q * c; k = kp * sn + k * c; }
    else       { q = q * c - qp * sn; k = k * c - kp * sn; }
  }
  q *= 0.125f;
  long o1 = ((long)(bb * NH_ + h) * SP_ + s) * 64 + d;
  qf[o1] = __float2bfloat16(q);
  kf[o1] = __float2bfloat16(k);
}

// ---------------- head gates: sigmoid(h @ gate_W + gate_b) ----------------
__global__ __launch_bounds__(64) void gate_k(const bf16* __restrict__ h, const float* __restrict__ gW,
                                             const float* __restrict__ gb, float* __restrict__ gate) {
  int tok = blockIdx.x, l = threadIdx.x;
  float hv[12];
#pragma unroll
  for (int i = 0; i < 12; i++) hv[i] = __bfloat162float(h[(long)tok * H_ + i * 64 + l]);
#pragma unroll
  for (int n = 0; n < 12; n++) {
    float s = 0.f;
#pragma unroll
    for (int i = 0; i < 12; i++) s += hv[i] * gW[(i * 64 + l) * 12 + n];
    for (int off = 32; off; off >>= 1) s += __shfl_xor(s, off);
    if (l == 0) gate[(long)tok * 12 + n] = 1.f / (1.f + __expf(-(s + gb[n])));
  }
}

// ---------------- flash attention, swapped QK^T, KVBLK=64, no LDS ----------------
// grid: 6336 blocks (XCD-swizzled), 1 wave each; 16 q rows per wave
__global__ __launch_bounds__(64) void attn_k(
    const bf16* __restrict__ qf, const bf16* __restrict__ kf, const bf16* __restrict__ vtf,
    const float* __restrict__ gate, bf16* __restrict__ attn_g) {
  int bid = blockIdx.x;
  int w = (bid & 7) * (6336 / 8) + (bid >> 3);   // XCD-pinned: 12 bh per XCD
  int bh = w / 66, qb = w - bh * 66;
  int bb = bh / NH_, h = bh - bb * NH_;
  int lane = threadIdx.x & 63;
  int lr = lane & 15, lg = lane >> 4;
  const bf16* qbase = qf + (long)bh * SP_ * 64;
  const bf16* kbase = kf + (long)bh * SP_ * 64;
  const bf16* vbase = vtf + (long)bh * 64 * SP_;

  int q_l = qb * 16 + lr;  // q row this lane owns (softmax state)
  bf16x8v qB0 = *(const bf16x8v*)(qbase + (long)q_l * 64 + lg * 8);
  bf16x8v qB1 = *(const bf16x8v*)(qbase + (long)q_l * 64 + 32 + lg * 8);

  f32x4 z; z[0] = z[1] = z[2] = z[3] = 0.f;
  f32x4 acc[4] = {z, z, z, z};
  float m = -1e30f, lsum = 0.f;

  for (int kt = 0; kt < SP_ / 64; kt++) {
    int kidx = kt * 64;
    // QK^T swapped: C[row=k][col=q]
    f32x4 p[4];
    __builtin_amdgcn_s_setprio(1);
#pragma unroll
    for (int mt = 0; mt < 4; mt++) {
      const bf16* kr = kbase + (long)(kidx + mt * 16 + lr) * 64 + lg * 8;
      bf16x8v k0 = *(const bf16x8v*)kr;
      bf16x8v k1 = *(const bf16x8v*)(kr + 32);
      f32x4 t = z;
      t = __builtin_amdgcn_mfma_f32_16x16x32_bf16(k0, qB0, t, 0, 0, 0);
      t = __builtin_amdgcn_mfma_f32_16x16x32_bf16(k1, qB1, t, 0, 0, 0);
      p[mt] = t;
    }
    __builtin_amdgcn_s_setprio(0);
    if (kidx + 64 > S_) {
#pragma unroll
      for (int mt = 0; mt < 4; mt++)
#pragma unroll
        for (int r = 0; r < 4; r++)
          if (kidx + mt * 16 + lg * 4 + r >= S_) p[mt][r] = -1e30f;
    }
    // softmax over k (this lane holds 16 of 64 k's for q=lr)
    float tmax = p[0][0];
#pragma unroll
    for (int mt = 0; mt < 4; mt++)
#pragma unroll
      for (int r = 0; r < 4; r++) tmax = fmaxf(tmax, p[mt][r]);
    tmax = fmaxf(tmax, __shfl_xor(tmax, 16));
    tmax = fmaxf(tmax, __shfl_xor(tmax, 32));
    float mn = fmaxf(m, tmax);
    float so = __expf(m - mn);
    float ts = 0.f;
#pragma unroll
    for (int mt = 0; mt < 4; mt++)
#pragma unroll
      for (int r = 0; r < 4; r++) {
        float e = __expf(p[mt][r] - mn);
        p[mt][r] = e;
        ts += e;
      }
    ts += __shfl_xor(ts, 16);
    ts += __shfl_xor(ts, 32);
    lsum = lsum * so + ts;
    m = mn;
    // rescale acc (acc rows are q=lg*4+r; softmax state lives at lane lr=q)
    float so4[4];
#pragma unroll
    for (int r = 0; r < 4; r++) so4[r] = __shfl(so, lg * 4 + r);
#pragma unroll
    for (int dt = 0; dt < 4; dt++) {
      f32x4 a = acc[dt];
      a[0] *= so4[0]; a[1] *= so4[1]; a[2] *= so4[2]; a[3] *= so4[3];
      acc[dt] = a;
    }
    // pack P to bf16 pairs: w0[mt]=k{lg*4+0,1}, w1[mt]=k{lg*4+2,3} of tile row mt*16
    uint32_t w0[4], w1[4];
#pragma unroll
    for (int mt = 0; mt < 4; mt++) {
      w0[mt] = packbf(p[mt][0], p[mt][1]);
      w1[mt] = packbf(p[mt][2], p[mt][3]);
    }
    // redistribute into PV A-frags: lane needs P[q=lr][k=t2*32+lg*8+2wd+{0,1}]
    bf16x8v aP[2];
#pragma unroll
    for (int t2 = 0; t2 < 2; t2++) {
      union { uint32_t u[4]; bf16x8v v; } cvt;
#pragma unroll
      for (int wd = 0; wd < 4; wd++) {
        uint32_t a = (wd & 1) ? w1[2 * t2] : w0[2 * t2];
        uint32_t b = (wd & 1) ? w1[2 * t2 + 1] : w0[2 * t2 + 1];
        uint32_t val = (lg & 2) ? b : a;
        int src = ((lg & 1) * 2 + (wd >> 1)) * 16 + lr;
        cvt.u[wd] = (uint32_t)__shfl((int)val, src);
      }
      aP[t2] = cvt.v;
    }
    // PV: acc[dt] += aP[t2] x V^T
    __builtin_amdgcn_s_setprio(1);
#pragma unroll
    for (int t2 = 0; t2 < 2; t2++)
#pragma unroll
      for (int dt = 0; dt < 4; dt++) {
        bf16x8v vB = *(const bf16x8v*)(vbase + (long)(dt * 16 + lr) * SP_ + kidx + t2 * 32 + lg * 8);
        acc[dt] = __builtin_amdgcn_mfma_f32_16x16x32_bf16(aP[t2], vB, acc[dt], 0, 0, 0);
      }
    __builtin_amdgcn_s_setprio(0);
  }
  // epilogue: out = acc * gate/lsum
  float norm = 0.f;
  if (q_l < S_) norm = gate[((long)bb * S_ + q_l) * 12 + h] / lsum;
  float nr[4];
#pragma unroll
  for (int r = 0; r < 4; r++) nr[r] = __shfl(norm, lg * 4 + r);
#pragma unroll
  for (int dt = 0; dt < 4; dt++)
#pragma unroll
    for (int r = 0; r < 4; r++) {
      int qr = qb * 16 + lg * 4 + r;
      if (qr < S_)
        attn_g[((long)bb * S_ + qr) * H_ + h * 64 + dt * 16 + lr] =
            __float2bfloat16(acc[dt][r] * nr[r]);
    }
}

// ---------------- silu(gate)*up ----------------
__global__ __launch_bounds__(256) void silu_mul_k(const bf16* __restrict__ gu, bf16* __restrict__ o) {
  long i = (long)blockIdx.x * 256 + threadIdx.x;
  long row = i >> 8;
  int c8 = (int)(i & 255) * 8;
  bf16x8v gv = *(const bf16x8v*)(gu + row * 4096 + c8);
  bf16x8v uv = *(const bf16x8v*)(gu + row * 4096 + 2048 + c8);
  bf16x8v ov;
#pragma unroll
  for (int j = 0; j < 8; j++) {
    short sg = gv[j], su = uv[j];
    float g = __bfloat162float(*reinterpret_cast<bf16*>(&sg));
    float u = __bfloat162float(*reinterpret_cast<bf16*>(&su));
    float s = g / (1.f + __expf(-g));
    bf16 r = __float2bfloat16(s * u);
    ov[j] = *reinterpret_cast<short*>(&r);
  }
  *(bf16x8v*)(o + row * 2048 + c8) = ov;
}

extern "C" void kernel_launch(void* const* d_in, const int* in_sizes, int n_in,
                              void* d_out, int out_size, void* d_ws, size_t ws_size,
                              hipStream_t stream) {
  const float* x    = (const float*)d_in[0];
  const float* cosT = (const float*)d_in[1];
  const float* sinT = (const float*)d_in[2];
  const float* Wq   = (const float*)d_in[3];
  const float* Wk   = (const float*)d_in[4];
  const float* Wv   = (const float*)d_in[5];
  const float* Wo   = (const float*)d_in[6];
  const float* qnw  = (const float*)d_in[7];
  const float* knw  = (const float*)d_in[8];
  const float* gW   = (const float*)d_in[9];
  const float* gb   = (const float*)d_in[10];
  const float* n1w  = (const float*)d_in[11];
  const float* n2w  = (const float*)d_in[12];
  const float* Wg   = (const float*)d_in[13];
  const float* Wu   = (const float*)d_in[14];
  const float* Wd   = (const float*)d_in[15];
  const float* ascale = (const float*)d_in[16];
  const float* mscale = (const float*)d_in[17];

  char* ws = (char*)d_ws;
  size_t off = 0;
  auto alloc = [&](size_t bytes) {
    char* p = ws + off;
    off += (bytes + 255) & ~(size_t)255;
    return p;
  };
  bf16* h_pad  = (bf16*)alloc((size_t)MP_ * H_ * 2);      // reused as h2
  bf16* wqkv_t = (bf16*)alloc((size_t)2304 * 768 * 2);
  bf16* wo_t   = (bf16*)alloc((size_t)768 * 768 * 2);
  bf16* wgu_t  = (bf16*)alloc((size_t)4096 * 768 * 2);
  bf16* wdn_t  = (bf16*)alloc((size_t)768 * 2048 * 2);
  bf16* qkv    = (bf16*)alloc((size_t)MP_ * 2304 * 2);    // reused as mlpin
  bf16* qfb    = (bf16*)alloc((size_t)96 * SP_ * 64 * 2);
  bf16* kfb    = (bf16*)alloc((size_t)96 * SP_ * 64 * 2);
  bf16* vtfb   = (bf16*)alloc((size_t)96 * SP_ * 64 * 2);
  float* gateb = (float*)alloc((size_t)T_ * 12 * 4);
  bf16* attn_g = (bf16*)alloc((size_t)MP_ * H_ * 2);
  float* x2    = (float*)alloc((size_t)T_ * H_ * 4);
  bf16* gu     = (bf16*)alloc((size_t)MP_ * 4096 * 2);
  bf16* mlpin  = qkv;

  // zero: vtf (pad cols must be finite/zero), attn_g pad rows
  fillz<<<1024, 256, 0, stream>>>((uint4*)vtfb, (long)(96 * SP_ * 64 * 2) / 16);
  fillz<<<64, 256, 0, stream>>>((uint4*)(attn_g + (long)T_ * H_), (long)((MP_ - T_) * H_ * 2) / 16);

  // weight conversion (LDS-tiled transpose to N x K, bf16)
  auto wc = [&](const float* W, bf16* o, int K, int N) {
    wcvt_t<<<dim3(K / 32, N / 32), 256, 0, stream>>>(W, o, K, N);
  };
  wc(Wq, wqkv_t, 768, 768);
  wc(Wk, wqkv_t + 768 * 768, 768, 768);
  wc(Wv, wqkv_t + 2 * 768 * 768, 768, 768);
  wc(Wo, wo_t, 768, 768);
  wc(Wg, wgu_t, 768, 2048);
  wc(Wu, wgu_t + (long)2048 * 768, 768, 2048);
  wc(Wd, wdn_t, 2048, 768);

  rmsnorm_k<<<MP_, 256, 0, stream>>>(x, n1w, h_pad, T_);

  gemm_bf16<0><<<dim3(2304 / 128, MP_ / 128), 256, 0, stream>>>(
      h_pad, wqkv_t, qkv, nullptr, nullptr, 2304, 768, MP_);

  qkv_post<<<T_, 768, 0, stream>>>(qkv, qnw, knw, cosT, sinT, qfb, kfb);
  vtran<<<dim3(33, 96), 256, 0, stream>>>(qkv, vtfb);

  gate_k<<<T_, 64, 0, stream>>>(h_pad, gW, gb, gateb);

  attn_k<<<6336, 64, 0, stream>>>(qfb, kfb, vtfb, gateb, attn_g);

  gemm_bf16<1><<<dim3(768 / 128, MP_ / 128), 256, 0, stream>>>(
      attn_g, wo_t, x2, x, ascale, 768, 768, T_);

  rmsnorm_k<<<MP_, 256, 0, stream>>>(x2, n2w, h_pad, T_);

  gemm_bf16<0><<<dim3(4096 / 128, MP_ / 128), 256, 0, stream>>>(
      h_pad, wgu_t, gu, nullptr, nullptr, 4096, 768, MP_);

  silu_mul_k<<<MP_, 256, 0, stream>>>(gu, mlpin);

  gemm_bf16<1><<<dim3(768 / 128, MP_ / 128), 256, 0, stream>>>(
      mlpin, wdn_t, (float*)d_out, x2, mscale, 768, 2048, T_);
}

// Round 3
// 488.711 us; speedup vs baseline: 1.2604x; 1.2604x over previous
//
#include <hip/hip_runtime.h>
#include <hip/hip_bf16.h>
#include <stdint.h>

#define B_   8
#define S_   1042
#define H_   768
#define NH_  12
#define HD_  64
#define MLP_ 2048
#define T_   (B_*S_)    // 8336 tokens
#define MP_  8448       // tokens padded to 66*128
#define SP_  1088       // seq padded to 17*64
#define EPS_ 1e-6f

typedef __attribute__((ext_vector_type(8))) short bf16x8v;
typedef __attribute__((ext_vector_type(4))) float f32x4;
typedef __hip_bfloat16 bf16;

typedef __attribute__((address_space(1))) const void gas_void;
typedef __attribute__((address_space(3))) void las_void;

__device__ inline void gload_lds16(const void* g, void* l) {
  __builtin_amdgcn_global_load_lds((gas_void*)g, (las_void*)l, 16, 0, 0);
}

// ---------------- zero fill ----------------
__global__ void fillz(uint4* p, long n16) {
  long i = (long)blockIdx.x * blockDim.x + threadIdx.x;
  long stride = (long)gridDim.x * blockDim.x;
  uint4 z; z.x = z.y = z.z = z.w = 0u;
  for (; i < n16; i += stride) p[i] = z;
}

// ---------------- weight convert + transpose (LDS-tiled): out[n*K+k] = W[k*N+n] ----------------
__global__ __launch_bounds__(256) void wcvt_t(const float* __restrict__ W, bf16* __restrict__ o,
                                              int K, int N) {
  __shared__ float tile[32][33];
  int kt = blockIdx.x, nt = blockIdx.y;
  int t = threadIdx.x;
  int r = t >> 5, c = t & 31;
#pragma unroll
  for (int i = 0; i < 4; i++)
    tile[i * 8 + r][c] = W[(long)(kt * 32 + i * 8 + r) * N + nt * 32 + c];
  __syncthreads();
#pragma unroll
  for (int i = 0; i < 4; i++)
    o[(long)(nt * 32 + i * 8 + r) * K + kt * 32 + c] = __float2bfloat16(tile[c][i * 8 + r]);
}

// ---------------- V transpose: qkv v-part -> vtf[(bh*64+d)*SP_+s] ----------------
__global__ __launch_bounds__(256) void vtran(const bf16* __restrict__ qkv, bf16* __restrict__ vtf) {
  __shared__ bf16 tile[32][66];
  int st = blockIdx.x, bh = blockIdx.y;
  int bb = bh / NH_, h = bh - bb * NH_;
  int s0 = st * 32;
  int t = threadIdx.x;
  int si = t >> 6, d = t & 63;
#pragma unroll
  for (int i = 0; i < 8; i++) {
    int s = s0 + i * 4 + si;
    bf16 v = __float2bfloat16(0.f);
    if (s < S_) v = qkv[(long)(bb * S_ + s) * 2304 + 1536 + h * 64 + d];
    tile[i * 4 + si][d] = v;
  }
  __syncthreads();
  int dd = t >> 5, sj = t & 31;
#pragma unroll
  for (int i = 0; i < 8; i++) {
    int d2 = i * 8 + dd;
    vtf[((long)bh * 64 + d2) * SP_ + s0 + sj] = tile[sj][d2];
  }
}

// ---------------- rmsnorm (768 wide), fp32 in -> bf16 out, zero pad rows ----------------
__global__ __launch_bounds__(256) void rmsnorm_k(const float* __restrict__ x,
                                                 const float* __restrict__ w,
                                                 bf16* __restrict__ o, int Mreal) {
  int row = blockIdx.x;
  bf16* orow = o + (long)row * H_;
  int t = threadIdx.x;
  if (row >= Mreal) {
    for (int i = t; i < H_; i += 256) orow[i] = __float2bfloat16(0.f);
    return;
  }
  const float* xr = x + (long)row * H_;
  float v0 = xr[t], v1 = xr[t + 256], v2 = xr[t + 512];
  float s = v0 * v0 + v1 * v1 + v2 * v2;
  for (int off = 32; off; off >>= 1) s += __shfl_down(s, off);
  __shared__ float red[4];
  if ((t & 63) == 0) red[t >> 6] = s;
  __syncthreads();
  float tot = red[0] + red[1] + red[2] + red[3];
  float inv = rsqrtf(tot * (1.f / H_) + EPS_);
  orow[t]       = __float2bfloat16(v0 * inv * w[t]);
  orow[t + 256] = __float2bfloat16(v1 * inv * w[t + 256]);
  orow[t + 512] = __float2bfloat16(v2 * inv * w[t + 512]);
}

// ---------------- bf16 GEMM: A (M x K, row-major) * Bt (N x K, row-major) ----------------
template <int EPI>
__global__ __launch_bounds__(256) void gemm_bf16(
    const bf16* __restrict__ A, const bf16* __restrict__ Bt, void* __restrict__ Out,
    const float* __restrict__ resid, const float* __restrict__ scale,
    int N, int K, int Mreal) {
  __shared__ __align__(16) bf16 As[128 * 32];
  __shared__ __align__(16) bf16 Bs[128 * 32];
  int tid = threadIdx.x;
  int lane = tid & 63, wid = tid >> 6;
  int wm = wid >> 1, wn = wid & 1;
  int lr = lane & 15, lg = lane >> 4;
  long rowA0 = (long)blockIdx.y * 128;
  long rowB0 = (long)blockIdx.x * 128;
  f32x4 z; z[0] = z[1] = z[2] = z[3] = 0.f;
  f32x4 acc[4][4];
#pragma unroll
  for (int mi = 0; mi < 4; mi++)
#pragma unroll
    for (int ni = 0; ni < 4; ni++) acc[mi][ni] = z;

  const int flat0 = wid * 512 + lane * 8;
  const bf16* Ab = A + rowA0 * K;
  const bf16* Bb = Bt + rowB0 * K;

  for (int k0 = 0; k0 < K; k0 += 32) {
    __syncthreads();
#pragma unroll
    for (int j = 0; j < 2; j++) {
      int flat = flat0 + j * 2048;
      int r = flat >> 5, c = flat & 31;
      gload_lds16(Ab + (long)r * K + k0 + c, &As[flat]);
      gload_lds16(Bb + (long)r * K + k0 + c, &Bs[flat]);
    }
    __syncthreads();
    bf16x8v af[4], bfr[4];
#pragma unroll
    for (int mi = 0; mi < 4; mi++)
      af[mi] = *(const bf16x8v*)&As[(wm * 64 + mi * 16 + lr) * 32 + lg * 8];
#pragma unroll
    for (int ni = 0; ni < 4; ni++)
      bfr[ni] = *(const bf16x8v*)&Bs[(wn * 64 + ni * 16 + lr) * 32 + lg * 8];
#pragma unroll
    for (int mi = 0; mi < 4; mi++)
#pragma unroll
      for (int ni = 0; ni < 4; ni++)
        acc[mi][ni] = __builtin_amdgcn_mfma_f32_16x16x32_bf16(af[mi], bfr[ni], acc[mi][ni], 0, 0, 0);
  }

#pragma unroll
  for (int mi = 0; mi < 4; mi++) {
#pragma unroll
    for (int ni = 0; ni < 4; ni++) {
#pragma unroll
      for (int r = 0; r < 4; r++) {
        long row = rowA0 + wm * 64 + mi * 16 + lg * 4 + r;
        long col = rowB0 + wn * 64 + ni * 16 + lr;
        float v = acc[mi][ni][r];
        if (EPI == 0) {
          ((bf16*)Out)[row * N + col] = __float2bfloat16(v);
        } else {
          if (row < Mreal)
            ((float*)Out)[row * N + col] = resid[row * N + col] + v * scale[col];
        }
      }
    }
  }
}

// ---------------- qk rmsnorm + rope + scale (q scaled to base-2 exp units) ----------------
__global__ __launch_bounds__(768) void qkv_post(
    const bf16* __restrict__ qkv, const float* __restrict__ qw, const float* __restrict__ kw,
    const float* __restrict__ cosT, const float* __restrict__ sinT,
    bf16* __restrict__ qf, bf16* __restrict__ kf) {
  int tok = blockIdx.x;
  int bb = tok / S_, s = tok - bb * S_;
  int h = threadIdx.x >> 6, d = threadIdx.x & 63;
  const bf16* base = qkv + (long)tok * 2304 + h * 64 + d;
  float q = __bfloat162float(base[0]);
  float k = __bfloat162float(base[768]);
  float qs = q * q, ks = k * k;
  for (int off = 32; off; off >>= 1) {
    qs += __shfl_xor(qs, off);
    ks += __shfl_xor(ks, off);
  }
  q *= rsqrtf(qs * (1.f / 64.f) + EPS_) * qw[d];
  k *= rsqrtf(ks * (1.f / 64.f) + EPS_) * kw[d];
  if (s >= S_ - 1024) {
    int pos = s - (S_ - 1024);
    int i = d >> 1;
    float c = cosT[pos * 32 + i], sn = sinT[pos * 32 + i];
    float qp = __shfl_xor(q, 1), kp = __shfl_xor(k, 1);
    if (d & 1) { q = qp * sn + q * c; k = kp * sn + k * c; }
    else       { q = q * c - qp * sn; k = k * c - kp * sn; }
  }
  q *= 0.125f * 1.44269504088896f;  // fold log2(e): softmax done in base 2
  long o1 = ((long)(bb * NH_ + h) * SP_ + s) * 64 + d;
  qf[o1] = __float2bfloat16(q);
  kf[o1] = __float2bfloat16(k);
}

// ---------------- head gates: sigmoid(h @ gate_W + gate_b) ----------------
__global__ __launch_bounds__(64) void gate_k(const bf16* __restrict__ h, const float* __restrict__ gW,
                                             const float* __restrict__ gb, float* __restrict__ gate) {
  int tok = blockIdx.x, l = threadIdx.x;
  float hv[12];
#pragma unroll
  for (int i = 0; i < 12; i++) hv[i] = __bfloat162float(h[(long)tok * H_ + i * 64 + l]);
#pragma unroll
  for (int n = 0; n < 12; n++) {
    float s = 0.f;
#pragma unroll
    for (int i = 0; i < 12; i++) s += hv[i] * gW[(i * 64 + l) * 12 + n];
    for (int off = 32; off; off >>= 1) s += __shfl_xor(s, off);
    if (l == 0) gate[(long)tok * 12 + n] = 1.f / (1.f + __expf(-(s + gb[n])));
  }
}

// swizzled LDS element offset for a [64][8x(8elem)] bf16 tile: row, colchunk cc
#define SWZ(row, cc) (((row) << 6) + ((((cc) ^ ((row) & 7))) << 3))

// ---------------- flash attention: 4 waves/block, 64 q-rows, LDS dbuf K/V ----------------
__global__ __launch_bounds__(256) void attn_k(
    const bf16* __restrict__ qf, const bf16* __restrict__ kf, const bf16* __restrict__ vtf,
    const float* __restrict__ gate, bf16* __restrict__ attn_g) {
  __shared__ __align__(16) bf16 Ks[2][64 * 64];
  __shared__ __align__(16) bf16 Vs[2][64 * 64];
  int bid = blockIdx.x;                      // 1632 = 8 * 204
  int w = (bid & 7) * 204 + (bid >> 3);      // XCD-pinned: 12 bh per XCD
  int bh = w / 17, qb = w - bh * 17;
  int bb = bh / NH_, h = bh - bb * NH_;
  int tid = threadIdx.x;
  int lane = tid & 63, wv = tid >> 6;
  int lr = lane & 15, lg = lane >> 4;
  const bf16* qbase = qf + (long)bh * SP_ * 64;
  const bf16* kbase = kf + (long)bh * SP_ * 64;
  const bf16* vbase = vtf + (long)bh * 64 * SP_;

  int q_l = qb * 64 + wv * 16 + lr;          // q row this lane owns (softmax state)
  bf16x8v qB0 = *(const bf16x8v*)(qbase + (long)q_l * 64 + lg * 8);
  bf16x8v qB1 = *(const bf16x8v*)(qbase + (long)q_l * 64 + 32 + lg * 8);

  f32x4 z; z[0] = z[1] = z[2] = z[3] = 0.f;
  f32x4 acc[4] = {z, z, z, z};
  float m = -1e30f, lsum = 0.f;

  // stage tile kt into buf: K 8KB + V 8KB, inverse-swizzled global source, linear LDS dest
  auto stage = [&](int buf, int kidx) {
#pragma unroll
    for (int inst = 0; inst < 2; inst++) {
      int c = inst * 256 + tid;
      int row = c >> 3, slot = c & 7;
      int cc = slot ^ (row & 7);
      gload_lds16(kbase + (long)(kidx + row) * 64 + cc * 8, &Ks[buf][c * 8]);
    }
#pragma unroll
    for (int inst = 0; inst < 2; inst++) {
      int c = inst * 256 + tid;
      int row = c >> 3, slot = c & 7;
      int cc = slot ^ (row & 7);
      gload_lds16(vbase + (long)row * SP_ + kidx + cc * 8, &Vs[buf][c * 8]);
    }
  };

  stage(0, 0);
  asm volatile("s_waitcnt vmcnt(0)" ::: "memory");
  __syncthreads();
  int cur = 0;

  for (int kt = 0; kt < SP_ / 64; kt++) {
    int kidx = kt * 64;
    if (kt < SP_ / 64 - 1) stage(cur ^ 1, kidx + 64);

    // QK^T swapped: C[row=k][col=q], K from LDS (swizzled)
    f32x4 p[4];
    __builtin_amdgcn_s_setprio(1);
#pragma unroll
    for (int mt = 0; mt < 4; mt++) {
      int row = mt * 16 + lr;
      bf16x8v k0 = *(const bf16x8v*)&Ks[cur][SWZ(row, lg)];
      bf16x8v k1 = *(const bf16x8v*)&Ks[cur][SWZ(row, lg + 4)];
      f32x4 t = z;
      t = __builtin_amdgcn_mfma_f32_16x16x32_bf16(k0, qB0, t, 0, 0, 0);
      t = __builtin_amdgcn_mfma_f32_16x16x32_bf16(k1, qB1, t, 0, 0, 0);
      p[mt] = t;
    }
    __builtin_amdgcn_s_setprio(0);

    if (kidx + 64 > S_) {
#pragma unroll
      for (int mt = 0; mt < 4; mt++)
#pragma unroll
        for (int r = 0; r < 4; r++)
          if (kidx + mt * 16 + lg * 4 + r >= S_) p[mt][r] = -1e30f;
    }

    // online softmax over k; lane owns q=lr, holds 16 of 64 k's
    float tmax = p[0][0];
#pragma unroll
    for (int mt = 0; mt < 4; mt++)
#pragma unroll
      for (int r = 0; r < 4; r++) tmax = fmaxf(tmax, p[mt][r]);
    tmax = fmaxf(tmax, __shfl_xor(tmax, 16));
    tmax = fmaxf(tmax, __shfl_xor(tmax, 32));

    // defer-max: rescale only when max grows materially (base-2 units)
    if (__ballot(tmax > m + 11.0f)) {
      float mn = fmaxf(m, tmax);
      float so = exp2f(m - mn);
      m = mn;
      lsum *= so;
      float so4[4];
#pragma unroll
      for (int r = 0; r < 4; r++) so4[r] = __shfl(so, lg * 4 + r);
#pragma unroll
      for (int dt = 0; dt < 4; dt++) {
        f32x4 a = acc[dt];
        a[0] *= so4[0]; a[1] *= so4[1]; a[2] *= so4[2]; a[3] *= so4[3];
        acc[dt] = a;
      }
    }
    float ts = 0.f;
#pragma unroll
    for (int mt = 0; mt < 4; mt++)
#pragma unroll
      for (int r = 0; r < 4; r++) {
        float e = exp2f(p[mt][r] - m);
        p[mt][r] = e;
        ts += e;
      }
    ts += __shfl_xor(ts, 16);
    ts += __shfl_xor(ts, 32);
    lsum += ts;

    // pack P to bf16 pairs via v_cvt_pk: w0=k{lg*4+0,1}, w1=k{lg*4+2,3} of row mt*16
    uint32_t w0[4], w1[4];
#pragma unroll
    for (int mt = 0; mt < 4; mt++) {
      asm("v_cvt_pk_bf16_f32 %0, %1, %2" : "=v"(w0[mt]) : "v"(p[mt][0]), "v"(p[mt][1]));
      asm("v_cvt_pk_bf16_f32 %0, %1, %2" : "=v"(w1[mt]) : "v"(p[mt][2]), "v"(p[mt][3]));
    }
    // redistribute into PV A-frags: lane needs P[q=lr][k=t2*32+lg*8+2wd+{0,1}]
    bf16x8v aP[2];
#pragma unroll
    for (int t2 = 0; t2 < 2; t2++) {
      union { uint32_t u[4]; bf16x8v v; } cvt;
#pragma unroll
      for (int wd = 0; wd < 4; wd++) {
        uint32_t a = (wd & 1) ? w1[2 * t2] : w0[2 * t2];
        uint32_t b = (wd & 1) ? w1[2 * t2 + 1] : w0[2 * t2 + 1];
        uint32_t val = (lg & 2) ? b : a;
        int src = ((lg & 1) * 2 + (wd >> 1)) * 16 + lr;
        cvt.u[wd] = (uint32_t)__shfl((int)val, src);
      }
      aP[t2] = cvt.v;
    }
    // PV from LDS V^T (swizzled): acc[dt] += aP[t2] x V
    __builtin_amdgcn_s_setprio(1);
#pragma unroll
    for (int t2 = 0; t2 < 2; t2++)
#pragma unroll
      for (int dt = 0; dt < 4; dt++) {
        int row = dt * 16 + lr;
        bf16x8v vB = *(const bf16x8v*)&Vs[cur][SWZ(row, t2 * 4 + lg)];
        acc[dt] = __builtin_amdgcn_mfma_f32_16x16x32_bf16(aP[t2], vB, acc[dt], 0, 0, 0);
      }
    __builtin_amdgcn_s_setprio(0);

    asm volatile("s_waitcnt vmcnt(0)" ::: "memory");
    __syncthreads();
    cur ^= 1;
  }

  // epilogue: out = acc * gate/lsum
  float norm = 0.f;
  if (q_l < S_) norm = gate[((long)bb * S_ + q_l) * 12 + h] / lsum;
  float nr[4];
#pragma unroll
  for (int r = 0; r < 4; r++) nr[r] = __shfl(norm, lg * 4 + r);
#pragma unroll
  for (int dt = 0; dt < 4; dt++)
#pragma unroll
    for (int r = 0; r < 4; r++) {
      int qr = qb * 64 + wv * 16 + lg * 4 + r;
      if (qr < S_)
        attn_g[((long)bb * S_ + qr) * H_ + h * 64 + dt * 16 + lr] =
            __float2bfloat16(acc[dt][r] * nr[r]);
    }
}

// ---------------- silu(gate)*up ----------------
__global__ __launch_bounds__(256) void silu_mul_k(const bf16* __restrict__ gu, bf16* __restrict__ o) {
  long i = (long)blockIdx.x * 256 + threadIdx.x;
  long row = i >> 8;
  int c8 = (int)(i & 255) * 8;
  bf16x8v gv = *(const bf16x8v*)(gu + row * 4096 + c8);
  bf16x8v uv = *(const bf16x8v*)(gu + row * 4096 + 2048 + c8);
  bf16x8v ov;
#pragma unroll
  for (int j = 0; j < 8; j++) {
    short sg = gv[j], su = uv[j];
    float g = __bfloat162float(*reinterpret_cast<bf16*>(&sg));
    float u = __bfloat162float(*reinterpret_cast<bf16*>(&su));
    float s = g / (1.f + __expf(-g));
    bf16 r = __float2bfloat16(s * u);
    ov[j] = *reinterpret_cast<short*>(&r);
  }
  *(bf16x8v*)(o + row * 2048 + c8) = ov;
}

extern "C" void kernel_launch(void* const* d_in, const int* in_sizes, int n_in,
                              void* d_out, int out_size, void* d_ws, size_t ws_size,
                              hipStream_t stream) {
  const float* x    = (const float*)d_in[0];
  const float* cosT = (const float*)d_in[1];
  const float* sinT = (const float*)d_in[2];
  const float* Wq   = (const float*)d_in[3];
  const float* Wk   = (const float*)d_in[4];
  const float* Wv   = (const float*)d_in[5];
  const float* Wo   = (const float*)d_in[6];
  const float* qnw  = (const float*)d_in[7];
  const float* knw  = (const float*)d_in[8];
  const float* gW   = (const float*)d_in[9];
  const float* gb   = (const float*)d_in[10];
  const float* n1w  = (const float*)d_in[11];
  const float* n2w  = (const float*)d_in[12];
  const float* Wg   = (const float*)d_in[13];
  const float* Wu   = (const float*)d_in[14];
  const float* Wd   = (const float*)d_in[15];
  const float* ascale = (const float*)d_in[16];
  const float* mscale = (const float*)d_in[17];

  char* ws = (char*)d_ws;
  size_t off = 0;
  auto alloc = [&](size_t bytes) {
    char* p = ws + off;
    off += (bytes + 255) & ~(size_t)255;
    return p;
  };
  bf16* h_pad  = (bf16*)alloc((size_t)MP_ * H_ * 2);      // reused as h2
  bf16* wqkv_t = (bf16*)alloc((size_t)2304 * 768 * 2);
  bf16* wo_t   = (bf16*)alloc((size_t)768 * 768 * 2);
  bf16* wgu_t  = (bf16*)alloc((size_t)4096 * 768 * 2);
  bf16* wdn_t  = (bf16*)alloc((size_t)768 * 2048 * 2);
  bf16* qkv    = (bf16*)alloc((size_t)MP_ * 2304 * 2);    // reused as mlpin
  bf16* qfb    = (bf16*)alloc((size_t)96 * SP_ * 64 * 2);
  bf16* kfb    = (bf16*)alloc((size_t)96 * SP_ * 64 * 2);
  bf16* vtfb   = (bf16*)alloc((size_t)96 * SP_ * 64 * 2);
  float* gateb = (float*)alloc((size_t)T_ * 12 * 4);
  bf16* attn_g = (bf16*)alloc((size_t)MP_ * H_ * 2);
  float* x2    = (float*)alloc((size_t)T_ * H_ * 4);
  bf16* gu     = (bf16*)alloc((size_t)MP_ * 4096 * 2);
  bf16* mlpin  = qkv;

  // zero: q/k (pad rows must be finite), vtf (pad cols), attn_g pad rows
  fillz<<<1024, 256, 0, stream>>>((uint4*)qfb, (long)(3 * 96 * SP_ * 64 * 2) / 16);
  fillz<<<64, 256, 0, stream>>>((uint4*)(attn_g + (long)T_ * H_), (long)((MP_ - T_) * H_ * 2) / 16);

  // weight conversion (LDS-tiled transpose to N x K, bf16)
  auto wc = [&](const float* W, bf16* o, int K, int N) {
    wcvt_t<<<dim3(K / 32, N / 32), 256, 0, stream>>>(W, o, K, N);
  };
  wc(Wq, wqkv_t, 768, 768);
  wc(Wk, wqkv_t + 768 * 768, 768, 768);
  wc(Wv, wqkv_t + 2 * 768 * 768, 768, 768);
  wc(Wo, wo_t, 768, 768);
  wc(Wg, wgu_t, 768, 2048);
  wc(Wu, wgu_t + (long)2048 * 768, 768, 2048);
  wc(Wd, wdn_t, 2048, 768);

  rmsnorm_k<<<MP_, 256, 0, stream>>>(x, n1w, h_pad, T_);

  gemm_bf16<0><<<dim3(2304 / 128, MP_ / 128), 256, 0, stream>>>(
      h_pad, wqkv_t, qkv, nullptr, nullptr, 2304, 768, MP_);

  qkv_post<<<T_, 768, 0, stream>>>(qkv, qnw, knw, cosT, sinT, qfb, kfb);
  vtran<<<dim3(33, 96), 256, 0, stream>>>(qkv, vtfb);

  gate_k<<<T_, 64, 0, stream>>>(h_pad, gW, gb, gateb);

  attn_k<<<1632, 256, 0, stream>>>(qfb, kfb, vtfb, gateb, attn_g);

  gemm_bf16<1><<<dim3(768 / 128, MP_ / 128), 256, 0, stream>>>(
      attn_g, wo_t, x2, x, ascale, 768, 768, T_);

  rmsnorm_k<<<MP_, 256, 0, stream>>>(x2, n2w, h_pad, T_);

  gemm_bf16<0><<<dim3(4096 / 128, MP_ / 128), 256, 0, stream>>>(
      h_pad, wgu_t, gu, nullptr, nullptr, 4096, 768, MP_);

  silu_mul_k<<<MP_, 256, 0, stream>>>(gu, mlpin);

  gemm_bf16<1><<<dim3(768 / 128, MP_ / 128), 256, 0, stream>>>(
      mlpin, wdn_t, (float*)d_out, x2, mscale, 768, 2048, T_);
}

// Round 4
// 468.330 us; speedup vs baseline: 1.3153x; 1.0435x over previous
//
#include <hip/hip_runtime.h>
#include <hip/hip_bf16.h>
#include <stdint.h>

#define B_   8
#define S_   1042
#define H_   768
#define NH_  12
#define HD_  64
#define MLP_ 2048
#define T_   (B_*S_)    // 8336 tokens
#define MP_  8448       // tokens padded to 66*128 (and 33*256)
#define SP_  1088       // seq padded to 17*64
#define EPS_ 1e-6f

typedef __attribute__((ext_vector_type(8))) short bf16x8v;
typedef __attribute__((ext_vector_type(4))) float f32x4;
typedef __hip_bfloat16 bf16;

typedef __attribute__((address_space(1))) const void gas_void;
typedef __attribute__((address_space(3))) void las_void;

__device__ inline void gload_lds16(const void* g, void* l) {
  __builtin_amdgcn_global_load_lds((gas_void*)g, (las_void*)l, 16, 0, 0);
}

#define BARRIER asm volatile("s_barrier" ::: "memory")
#define VMCNT4  asm volatile("s_waitcnt vmcnt(4)" ::: "memory")

// ---------------- weight convert + transpose (LDS-tiled): out[n*K+k] = W[k*N+n] ----------------
__global__ __launch_bounds__(256) void wcvt_t(const float* __restrict__ W, bf16* __restrict__ o,
                                              int K, int N) {
  __shared__ float tile[32][33];
  int kt = blockIdx.x, nt = blockIdx.y;
  int t = threadIdx.x;
  int r = t >> 5, c = t & 31;
#pragma unroll
  for (int i = 0; i < 4; i++)
    tile[i * 8 + r][c] = W[(long)(kt * 32 + i * 8 + r) * N + nt * 32 + c];
  __syncthreads();
#pragma unroll
  for (int i = 0; i < 4; i++)
    o[(long)(nt * 32 + i * 8 + r) * K + kt * 32 + c] = __float2bfloat16(tile[c][i * 8 + r]);
}

// ---------------- gate/up interleaved weight transpose ----------------
// out row n (0..4095), K=768: src col c=(n>>5)*16+(n&15); gate if ((n>>4)&1)==0 else up
__global__ __launch_bounds__(256) void wcvt_gu(const float* __restrict__ Wg,
                                               const float* __restrict__ Wu,
                                               bf16* __restrict__ o) {
  __shared__ float tile[32][33];
  int kt = blockIdx.x, nt = blockIdx.y;   // k-tile (24), n-tile (128)
  int t = threadIdx.x;
  int r = t >> 5, c = t & 31;
  const float* src = (c < 16) ? Wg : Wu;
  int col = nt * 16 + (c & 15);
#pragma unroll
  for (int i = 0; i < 4; i++)
    tile[i * 8 + r][c] = src[(long)(kt * 32 + i * 8 + r) * MLP_ + col];
  __syncthreads();
#pragma unroll
  for (int i = 0; i < 4; i++)
    o[(long)(nt * 32 + i * 8 + r) * 768 + kt * 32 + c] = __float2bfloat16(tile[c][i * 8 + r]);
}

// ---------------- rmsnorm (768 wide), fp32 in -> bf16 out, zero pad rows ----------------
__global__ __launch_bounds__(256) void rmsnorm_k(const float* __restrict__ x,
                                                 const float* __restrict__ w,
                                                 bf16* __restrict__ o, int Mreal) {
  int row = blockIdx.x;
  bf16* orow = o + (long)row * H_;
  int t = threadIdx.x;
  if (row >= Mreal) {
    for (int i = t; i < H_; i += 256) orow[i] = __float2bfloat16(0.f);
    return;
  }
  const float* xr = x + (long)row * H_;
  float v0 = xr[t], v1 = xr[t + 256], v2 = xr[t + 512];
  float s = v0 * v0 + v1 * v1 + v2 * v2;
  for (int off = 32; off; off >>= 1) s += __shfl_down(s, off);
  __shared__ float red[4];
  if ((t & 63) == 0) red[t >> 6] = s;
  __syncthreads();
  float tot = red[0] + red[1] + red[2] + red[3];
  float inv = rsqrtf(tot * (1.f / H_) + EPS_);
  orow[t]       = __float2bfloat16(v0 * inv * w[t]);
  orow[t + 256] = __float2bfloat16(v1 * inv * w[t + 256]);
  orow[t + 512] = __float2bfloat16(v2 * inv * w[t + 512]);
}

// ======== 256x256 8-phase GEMM, K=768 fixed, BK=64, 8 waves ========
// A (M x 768 row-major), Bt (N x 768 row-major). EPI 0: bf16 out (ld=N).
// EPI 2: silu-fused gate/up interleaved -> bf16 out ld=2048.
template <int EPI>
__global__ __launch_bounds__(512) void gemm256(
    const bf16* __restrict__ A, const bf16* __restrict__ Bt, void* __restrict__ Out,
    int N, int nbn) {
  // LDS: [buf][region: A-half0, A-half1, B-half0, B-half1][128 rows x 64 k]
  __shared__ __align__(16) bf16 lds[2][4][128 * 64];
  int tid = threadIdx.x;
  int lane = tid & 63, wid = tid >> 6;
  int wr = wid >> 2, wc = wid & 3;         // wave grid 2(M) x 4(N)
  int lr = lane & 15, lg = lane >> 4;

  // XCD-bijective block swizzle (m204)
  int nwg = gridDim.x;
  int bid = blockIdx.x;
  int q = nwg >> 3, r8 = nwg & 7;
  int xcd = bid & 7, idx = bid >> 3;
  int wg = (xcd < r8 ? xcd * (q + 1) : r8 * (q + 1) + (xcd - r8) * q) + idx;
  int bm = wg / nbn, bn = wg - bm * nbn;

  // staging source addresses (per-thread invariant part)
  int chunk_row = tid >> 3;                      // 0..63
  int cc = (tid & 7) ^ (chunk_row & 7);          // inverse-swizzled chunk
  const bf16* aSrc = A + ((long)bm * 256 + chunk_row) * 768 + cc * 8;
  const bf16* bSrc = Bt + ((long)bn * 256 + chunk_row) * 768 + cc * 8;

  auto stA = [&](int buf, int half, int kt) {
    bf16* d = &lds[buf][half][tid * 8];
    const bf16* s = aSrc + (long)half * 128 * 768 + kt * 64;
    gload_lds16(s, d);
    gload_lds16(s + 64 * 768, d + 512 * 8);
  };
  auto stB = [&](int buf, int half, int kt) {
    bf16* d = &lds[buf][2 + half][tid * 8];
    const bf16* s = bSrc + (long)half * 128 * 768 + kt * 64;
    gload_lds16(s, d);
    gload_lds16(s + 64 * 768, d + 512 * 8);
  };
  auto ldA = [&](int buf, int mi, int ks) -> bf16x8v {
    int row = mi * 16 + lr;
    int c = (ks * 4 + lg) ^ (row & 7);
    return *(const bf16x8v*)&lds[buf][wr][row * 64 + c * 8];
  };
  auto ldB = [&](int buf, int ni, int ks) -> bf16x8v {
    int row = (wc & 1) * 64 + ni * 16 + lr;
    int c = (ks * 4 + lg) ^ (row & 7);
    return *(const bf16x8v*)&lds[buf][2 + (wc >> 1)][row * 64 + c * 8];
  };

  f32x4 z; z[0] = z[1] = z[2] = z[3] = 0.f;
  f32x4 acc[8][4];
#pragma unroll
  for (int mi = 0; mi < 8; mi++)
#pragma unroll
    for (int ni = 0; ni < 4; ni++) acc[mi][ni] = z;

  bf16x8v bf[4][2];   // B frags for current tile (live across its 4 phases)
  bf16x8v af[4];      // A frags for current phase

  // prologue: tile0 full + tile1 B-halves
  stA(0, 0, 0); stA(0, 1, 0); stB(0, 0, 0); stB(0, 1, 0);
  stB(1, 0, 1); stB(1, 1, 1);
  VMCNT4;           // tile0 fully landed (leaves tile1 B in flight)
  BARRIER;

#define PHASE(p, bb, STG, VM)                                                   \
  {                                                                             \
    if ((p) == 0) {                                                             \
      _Pragma("unroll") for (int ni = 0; ni < 4; ni++) {                        \
        bf[ni][0] = ldB(bb, ni, 0); bf[ni][1] = ldB(bb, ni, 1);                 \
      }                                                                         \
    }                                                                           \
    af[0] = ldA(bb, 2 * (p), 0);     af[1] = ldA(bb, 2 * (p), 1);               \
    af[2] = ldA(bb, 2 * (p) + 1, 0); af[3] = ldA(bb, 2 * (p) + 1, 1);           \
    STG;                                                                        \
    asm volatile("" ::: "memory");                                              \
    BARRIER;                                                                    \
    __builtin_amdgcn_s_setprio(1);                                              \
    _Pragma("unroll") for (int dm = 0; dm < 2; dm++)                            \
      _Pragma("unroll") for (int ni = 0; ni < 4; ni++) {                        \
        acc[2 * (p) + dm][ni] = __builtin_amdgcn_mfma_f32_16x16x32_bf16(        \
            af[dm * 2 + 0], bf[ni][0], acc[2 * (p) + dm][ni], 0, 0, 0);         \
        acc[2 * (p) + dm][ni] = __builtin_amdgcn_mfma_f32_16x16x32_bf16(        \
            af[dm * 2 + 1], bf[ni][1], acc[2 * (p) + dm][ni], 0, 0, 0);         \
      }                                                                         \
    __builtin_amdgcn_s_setprio(0);                                              \
    if (VM) VMCNT4;                                                             \
    BARRIER;                                                                    \
  }

  for (int i = 0; i < 6; i++) {
    int u = 2 * i + 1;
    int t2 = (2 * i + 2 < 12) ? 2 * i + 2 : 11;
    int t3 = (2 * i + 3 < 12) ? 2 * i + 3 : 11;
    // tile 2i from buf0, staging per the race-free map
    PHASE(0, 0, stA(1, 0, u), 0);
    PHASE(1, 0, stA(1, 1, u), 0);
    PHASE(2, 0, stB(0, 0, t2), 0);
    PHASE(3, 0, stB(0, 1, t2), 1);
    // tile 2i+1 from buf1
    PHASE(0, 1, stA(0, 0, t2), 0);
    PHASE(1, 1, stA(0, 1, t2), 0);
    PHASE(2, 1, stB(1, 0, t3), 0);
    PHASE(3, 1, stB(1, 1, t3), 1);
  }
#undef PHASE

  // epilogue
  long rowbase = (long)bm * 256 + wr * 128;
  int colbase = bn * 256 + wc * 64;
  if (EPI == 0) {
    bf16* O = (bf16*)Out;
#pragma unroll
    for (int mi = 0; mi < 8; mi++)
#pragma unroll
      for (int ni = 0; ni < 4; ni++)
#pragma unroll
        for (int r = 0; r < 4; r++)
          O[(rowbase + mi * 16 + lg * 4 + r) * N + colbase + ni * 16 + lr] =
              __float2bfloat16(acc[mi][ni][r]);
  } else {
    bf16* O = (bf16*)Out;
    int oc0 = colbase >> 1;
#pragma unroll
    for (int mi = 0; mi < 8; mi++)
#pragma unroll
      for (int p = 0; p < 2; p++)
#pragma unroll
        for (int r = 0; r < 4; r++) {
          float g = acc[mi][2 * p][r], u = acc[mi][2 * p + 1][r];
          float v = g / (1.f + __expf(-g)) * u;
          O[(rowbase + mi * 16 + lg * 4 + r) * 2048 + oc0 + p * 16 + lr] =
              __float2bfloat16(v);
        }
  }
}

// ---------------- old 128x128 GEMM (kept for Wo / MLP2): EPI1 fp32 resid+scale ----------------
template <int EPI>
__global__ __launch_bounds__(256) void gemm_bf16(
    const bf16* __restrict__ A, const bf16* __restrict__ Bt, void* __restrict__ Out,
    const float* __restrict__ resid, const float* __restrict__ scale,
    int N, int K, int Mreal) {
  __shared__ __align__(16) bf16 As[128 * 32];
  __shared__ __align__(16) bf16 Bs[128 * 32];
  int tid = threadIdx.x;
  int lane = tid & 63, wid = tid >> 6;
  int wm = wid >> 1, wn = wid & 1;
  int lr = lane & 15, lg = lane >> 4;
  long rowA0 = (long)blockIdx.y * 128;
  long rowB0 = (long)blockIdx.x * 128;
  f32x4 z; z[0] = z[1] = z[2] = z[3] = 0.f;
  f32x4 acc[4][4];
#pragma unroll
  for (int mi = 0; mi < 4; mi++)
#pragma unroll
    for (int ni = 0; ni < 4; ni++) acc[mi][ni] = z;

  const int flat0 = wid * 512 + lane * 8;
  const bf16* Ab = A + rowA0 * K;
  const bf16* Bb = Bt + rowB0 * K;

  for (int k0 = 0; k0 < K; k0 += 32) {
    __syncthreads();
#pragma unroll
    for (int j = 0; j < 2; j++) {
      int flat = flat0 + j * 2048;
      int r = flat >> 5, c = flat & 31;
      gload_lds16(Ab + (long)r * K + k0 + c, &As[flat]);
      gload_lds16(Bb + (long)r * K + k0 + c, &Bs[flat]);
    }
    __syncthreads();
    bf16x8v af[4], bfr[4];
#pragma unroll
    for (int mi = 0; mi < 4; mi++)
      af[mi] = *(const bf16x8v*)&As[(wm * 64 + mi * 16 + lr) * 32 + lg * 8];
#pragma unroll
    for (int ni = 0; ni < 4; ni++)
      bfr[ni] = *(const bf16x8v*)&Bs[(wn * 64 + ni * 16 + lr) * 32 + lg * 8];
#pragma unroll
    for (int mi = 0; mi < 4; mi++)
#pragma unroll
      for (int ni = 0; ni < 4; ni++)
        acc[mi][ni] = __builtin_amdgcn_mfma_f32_16x16x32_bf16(af[mi], bfr[ni], acc[mi][ni], 0, 0, 0);
  }

#pragma unroll
  for (int mi = 0; mi < 4; mi++) {
#pragma unroll
    for (int ni = 0; ni < 4; ni++) {
#pragma unroll
      for (int r = 0; r < 4; r++) {
        long row = rowA0 + wm * 64 + mi * 16 + lg * 4 + r;
        long col = rowB0 + wn * 64 + ni * 16 + lr;
        float v = acc[mi][ni][r];
        if (EPI == 0) {
          ((bf16*)Out)[row * N + col] = __float2bfloat16(v);
        } else {
          if (row < Mreal)
            ((float*)Out)[row * N + col] = resid[row * N + col] + v * scale[col];
        }
      }
    }
  }
}

// ---------------- V transpose: qkv v-part -> vtf[(bh*64+d)*SP_+s] ----------------
__global__ __launch_bounds__(256) void vtran(const bf16* __restrict__ qkv, bf16* __restrict__ vtf) {
  __shared__ bf16 tile[32][66];
  int st = blockIdx.x, bh = blockIdx.y;
  int bb = bh / NH_, h = bh - bb * NH_;
  int s0 = st * 32;
  int t = threadIdx.x;
  int si = t >> 6, d = t & 63;
#pragma unroll
  for (int i = 0; i < 8; i++) {
    int s = s0 + i * 4 + si;
    bf16 v = __float2bfloat16(0.f);
    if (s < S_) v = qkv[(long)(bb * S_ + s) * 2304 + 1536 + h * 64 + d];
    tile[i * 4 + si][d] = v;
  }
  __syncthreads();
  int dd = t >> 5, sj = t & 31;
#pragma unroll
  for (int i = 0; i < 8; i++) {
    int d2 = i * 8 + dd;
    vtf[((long)bh * 64 + d2) * SP_ + s0 + sj] = tile[sj][d2];
  }
}

// ---------------- qk rmsnorm + rope + scale (q scaled to base-2 exp units) ----------------
__global__ __launch_bounds__(768) void qkv_post(
    const bf16* __restrict__ qkv, const float* __restrict__ qw, const float* __restrict__ kw,
    const float* __restrict__ cosT, const float* __restrict__ sinT,
    bf16* __restrict__ qf, bf16* __restrict__ kf) {
  int tok = blockIdx.x;
  int bb = tok / S_, s = tok - bb * S_;
  int h = threadIdx.x >> 6, d = threadIdx.x & 63;
  const bf16* base = qkv + (long)tok * 2304 + h * 64 + d;
  float q = __bfloat162float(base[0]);
  float k = __bfloat162float(base[768]);
  float qs = q * q, ks = k * k;
  for (int off = 32; off; off >>= 1) {
    qs += __shfl_xor(qs, off);
    ks += __shfl_xor(ks, off);
  }
  q *= rsqrtf(qs * (1.f / 64.f) + EPS_) * qw[d];
  k *= rsqrtf(ks * (1.f / 64.f) + EPS_) * kw[d];
  if (s >= S_ - 1024) {
    int pos = s - (S_ - 1024);
    int i = d >> 1;
    float c = cosT[pos * 32 + i], sn = sinT[pos * 32 + i];
    float qp = __shfl_xor(q, 1), kp = __shfl_xor(k, 1);
    if (d & 1) { q = qp * sn + q * c; k = kp * sn + k * c; }
    else       { q = q * c - qp * sn; k = k * c - kp * sn; }
  }
  q *= 0.125f * 1.44269504088896f;  // fold log2(e): softmax done in base 2
  long o1 = ((long)(bb * NH_ + h) * SP_ + s) * 64 + d;
  qf[o1] = __float2bfloat16(q);
  kf[o1] = __float2bfloat16(k);
}

// ---------------- head gates: sigmoid(h @ gate_W + gate_b) ----------------
__global__ __launch_bounds__(64) void gate_k(const bf16* __restrict__ h, const float* __restrict__ gW,
                                             const float* __restrict__ gb, float* __restrict__ gate) {
  int tok = blockIdx.x, l = threadIdx.x;
  float hv[12];
#pragma unroll
  for (int i = 0; i < 12; i++) hv[i] = __bfloat162float(h[(long)tok * H_ + i * 64 + l]);
#pragma unroll
  for (int n = 0; n < 12; n++) {
    float s = 0.f;
#pragma unroll
    for (int i = 0; i < 12; i++) s += hv[i] * gW[(i * 64 + l) * 12 + n];
    for (int off = 32; off; off >>= 1) s += __shfl_xor(s, off);
    if (l == 0) gate[(long)tok * 12 + n] = 1.f / (1.f + __expf(-(s + gb[n])));
  }
}

// swizzled LDS element offset for a [64][8x(8elem)] bf16 tile: row, colchunk cc
#define SWZ(row, cc) (((row) << 6) + ((((cc) ^ ((row) & 7))) << 3))

// ---------------- flash attention: 4 waves/block, 64 q-rows, LDS dbuf K/V ----------------
__global__ __launch_bounds__(256) void attn_k(
    const bf16* __restrict__ qf, const bf16* __restrict__ kf, const bf16* __restrict__ vtf,
    const float* __restrict__ gate, bf16* __restrict__ attn_g) {
  __shared__ __align__(16) bf16 Ks[2][64 * 64];
  __shared__ __align__(16) bf16 Vs[2][64 * 64];
  int bid = blockIdx.x;                      // 1632 = 8 * 204
  int w = (bid & 7) * 204 + (bid >> 3);      // XCD-pinned: 12 bh per XCD
  int bh = w / 17, qb = w - bh * 17;
  int bb = bh / NH_, h = bh - bb * NH_;
  int tid = threadIdx.x;
  int lane = tid & 63, wv = tid >> 6;
  int lr = lane & 15, lg = lane >> 4;
  const bf16* qbase = qf + (long)bh * SP_ * 64;
  const bf16* kbase = kf + (long)bh * SP_ * 64;
  const bf16* vbase = vtf + (long)bh * 64 * SP_;

  int q_l = qb * 64 + wv * 16 + lr;          // q row this lane owns (softmax state)
  bf16x8v qB0 = *(const bf16x8v*)(qbase + (long)q_l * 64 + lg * 8);
  bf16x8v qB1 = *(const bf16x8v*)(qbase + (long)q_l * 64 + 32 + lg * 8);

  f32x4 z; z[0] = z[1] = z[2] = z[3] = 0.f;
  f32x4 acc[4] = {z, z, z, z};
  float m = -1e30f, lsum = 0.f;

  auto stage = [&](int buf, int kidx) {
#pragma unroll
    for (int inst = 0; inst < 2; inst++) {
      int c = inst * 256 + tid;
      int row = c >> 3, slot = c & 7;
      int cc = slot ^ (row & 7);
      gload_lds16(kbase + (long)(kidx + row) * 64 + cc * 8, &Ks[buf][c * 8]);
    }
#pragma unroll
    for (int inst = 0; inst < 2; inst++) {
      int c = inst * 256 + tid;
      int row = c >> 3, slot = c & 7;
      int cc = slot ^ (row & 7);
      gload_lds16(vbase + (long)row * SP_ + kidx + cc * 8, &Vs[buf][c * 8]);
    }
  };

  stage(0, 0);
  asm volatile("s_waitcnt vmcnt(0)" ::: "memory");
  __syncthreads();
  int cur = 0;

  for (int kt = 0; kt < SP_ / 64; kt++) {
    int kidx = kt * 64;
    if (kt < SP_ / 64 - 1) stage(cur ^ 1, kidx + 64);

    f32x4 p[4];
    __builtin_amdgcn_s_setprio(1);
#pragma unroll
    for (int mt = 0; mt < 4; mt++) {
      int row = mt * 16 + lr;
      bf16x8v k0 = *(const bf16x8v*)&Ks[cur][SWZ(row, lg)];
      bf16x8v k1 = *(const bf16x8v*)&Ks[cur][SWZ(row, lg + 4)];
      f32x4 t = z;
      t = __builtin_amdgcn_mfma_f32_16x16x32_bf16(k0, qB0, t, 0, 0, 0);
      t = __builtin_amdgcn_mfma_f32_16x16x32_bf16(k1, qB1, t, 0, 0, 0);
      p[mt] = t;
    }
    __builtin_amdgcn_s_setprio(0);

    if (kidx + 64 > S_) {
#pragma unroll
      for (int mt = 0; mt < 4; mt++)
#pragma unroll
        for (int r = 0; r < 4; r++)
          if (kidx + mt * 16 + lg * 4 + r >= S_) p[mt][r] = -1e30f;
    }

    float tmax = p[0][0];
#pragma unroll
    for (int mt = 0; mt < 4; mt++)
#pragma unroll
      for (int r = 0; r < 4; r++) tmax = fmaxf(tmax, p[mt][r]);
    tmax = fmaxf(tmax, __shfl_xor(tmax, 16));
    tmax = fmaxf(tmax, __shfl_xor(tmax, 32));

    if (__ballot(tmax > m + 11.0f)) {
      float mn = fmaxf(m, tmax);
      float so = exp2f(m - mn);
      m = mn;
      lsum *= so;
      float so4[4];
#pragma unroll
      for (int r = 0; r < 4; r++) so4[r] = __shfl(so, lg * 4 + r);
#pragma unroll
      for (int dt = 0; dt < 4; dt++) {
        f32x4 a = acc[dt];
        a[0] *= so4[0]; a[1] *= so4[1]; a[2] *= so4[2]; a[3] *= so4[3];
        acc[dt] = a;
      }
    }
    float ts = 0.f;
#pragma unroll
    for (int mt = 0; mt < 4; mt++)
#pragma unroll
      for (int r = 0; r < 4; r++) {
        float e = exp2f(p[mt][r] - m);
        p[mt][r] = e;
        ts += e;
      }
    ts += __shfl_xor(ts, 16);
    ts += __shfl_xor(ts, 32);
    lsum += ts;

    uint32_t w0[4], w1[4];
#pragma unroll
    for (int mt = 0; mt < 4; mt++) {
      asm("v_cvt_pk_bf16_f32 %0, %1, %2" : "=v"(w0[mt]) : "v"(p[mt][0]), "v"(p[mt][1]));
      asm("v_cvt_pk_bf16_f32 %0, %1, %2" : "=v"(w1[mt]) : "v"(p[mt][2]), "v"(p[mt][3]));
    }
    bf16x8v aP[2];
#pragma unroll
    for (int t2 = 0; t2 < 2; t2++) {
      union { uint32_t u[4]; bf16x8v v; } cvt;
#pragma unroll
      for (int wd = 0; wd < 4; wd++) {
        uint32_t a = (wd & 1) ? w1[2 * t2] : w0[2 * t2];
        uint32_t b = (wd & 1) ? w1[2 * t2 + 1] : w0[2 * t2 + 1];
        uint32_t val = (lg & 2) ? b : a;
        int src = ((lg & 1) * 2 + (wd >> 1)) * 16 + lr;
        cvt.u[wd] = (uint32_t)__shfl((int)val, src);
      }
      aP[t2] = cvt.v;
    }
    __builtin_amdgcn_s_setprio(1);
#pragma unroll
    for (int t2 = 0; t2 < 2; t2++)
#pragma unroll
      for (int dt = 0; dt < 4; dt++) {
        int row = dt * 16 + lr;
        bf16x8v vB = *(const bf16x8v*)&Vs[cur][SWZ(row, t2 * 4 + lg)];
        acc[dt] = __builtin_amdgcn_mfma_f32_16x16x32_bf16(aP[t2], vB, acc[dt], 0, 0, 0);
      }
    __builtin_amdgcn_s_setprio(0);

    asm volatile("s_waitcnt vmcnt(0)" ::: "memory");
    __syncthreads();
    cur ^= 1;
  }

  float norm = 0.f;
  if (q_l < S_) norm = gate[((long)bb * S_ + q_l) * 12 + h] / lsum;
  float nr[4];
#pragma unroll
  for (int r = 0; r < 4; r++) nr[r] = __shfl(norm, lg * 4 + r);
#pragma unroll
  for (int dt = 0; dt < 4; dt++)
#pragma unroll
    for (int r = 0; r < 4; r++) {
      int qr = qb * 64 + wv * 16 + lg * 4 + r;
      if (qr < S_)
        attn_g[((long)bb * S_ + qr) * H_ + h * 64 + dt * 16 + lr] =
            __float2bfloat16(acc[dt][r] * nr[r]);
    }
}

extern "C" void kernel_launch(void* const* d_in, const int* in_sizes, int n_in,
                              void* d_out, int out_size, void* d_ws, size_t ws_size,
                              hipStream_t stream) {
  const float* x    = (const float*)d_in[0];
  const float* cosT = (const float*)d_in[1];
  const float* sinT = (const float*)d_in[2];
  const float* Wq   = (const float*)d_in[3];
  const float* Wk   = (const float*)d_in[4];
  const float* Wv   = (const float*)d_in[5];
  const float* Wo   = (const float*)d_in[6];
  const float* qnw  = (const float*)d_in[7];
  const float* knw  = (const float*)d_in[8];
  const float* gW   = (const float*)d_in[9];
  const float* gb   = (const float*)d_in[10];
  const float* n1w  = (const float*)d_in[11];
  const float* n2w  = (const float*)d_in[12];
  const float* Wg   = (const float*)d_in[13];
  const float* Wu   = (const float*)d_in[14];
  const float* Wd   = (const float*)d_in[15];
  const float* ascale = (const float*)d_in[16];
  const float* mscale = (const float*)d_in[17];

  char* ws = (char*)d_ws;
  size_t off = 0;
  auto alloc = [&](size_t bytes) {
    char* p = ws + off;
    off += (bytes + 255) & ~(size_t)255;
    return p;
  };
  bf16* h_pad  = (bf16*)alloc((size_t)MP_ * H_ * 2);      // reused as h2
  bf16* wqkv_t = (bf16*)alloc((size_t)2304 * 768 * 2);
  bf16* wo_t   = (bf16*)alloc((size_t)768 * 768 * 2);
  bf16* wgu_t  = (bf16*)alloc((size_t)4096 * 768 * 2);    // gate/up 16-col interleaved
  bf16* wdn_t  = (bf16*)alloc((size_t)768 * 2048 * 2);
  bf16* qkv    = (bf16*)alloc((size_t)MP_ * 2304 * 2);    // reused as mlpin (MP_*2048)
  bf16* qfb    = (bf16*)alloc((size_t)96 * SP_ * 64 * 2);
  bf16* kfb    = (bf16*)alloc((size_t)96 * SP_ * 64 * 2);
  bf16* vtfb   = (bf16*)alloc((size_t)96 * SP_ * 64 * 2);
  float* gateb = (float*)alloc((size_t)T_ * 12 * 4);
  bf16* attn_g = (bf16*)alloc((size_t)MP_ * H_ * 2);
  float* x2    = (float*)alloc((size_t)T_ * H_ * 4);
  bf16* mlpin  = qkv;

  // weight conversion
  auto wc = [&](const float* W, bf16* o, int K, int N) {
    wcvt_t<<<dim3(K / 32, N / 32), 256, 0, stream>>>(W, o, K, N);
  };
  wc(Wq, wqkv_t, 768, 768);
  wc(Wk, wqkv_t + 768 * 768, 768, 768);
  wc(Wv, wqkv_t + 2 * 768 * 768, 768, 768);
  wc(Wo, wo_t, 768, 768);
  wc(Wd, wdn_t, 2048, 768);
  wcvt_gu<<<dim3(24, 128), 256, 0, stream>>>(gW ? Wg : Wg, Wu, wgu_t);

  rmsnorm_k<<<MP_, 256, 0, stream>>>(x, n1w, h_pad, T_);

  gemm256<0><<<9 * 33, 512, 0, stream>>>(h_pad, wqkv_t, qkv, 2304, 9);

  qkv_post<<<T_, 768, 0, stream>>>(qkv, qnw, knw, cosT, sinT, qfb, kfb);
  vtran<<<dim3(33, 96), 256, 0, stream>>>(qkv, vtfb);

  gate_k<<<T_, 64, 0, stream>>>(h_pad, gW, gb, gateb);

  attn_k<<<1632, 256, 0, stream>>>(qfb, kfb, vtfb, gateb, attn_g);

  gemm_bf16<1><<<dim3(768 / 128, MP_ / 128), 256, 0, stream>>>(
      attn_g, wo_t, x2, x, ascale, 768, 768, T_);

  rmsnorm_k<<<MP_, 256, 0, stream>>>(x2, n2w, h_pad, T_);

  gemm256<2><<<16 * 33, 512, 0, stream>>>(h_pad, wgu_t, mlpin, 4096, 16);

  gemm_bf16<1><<<dim3(768 / 128, MP_ / 128), 256, 0, stream>>>(
      mlpin, wdn_t, (float*)d_out, x2, mscale, 768, 2048, T_);
}

// Round 5
// 414.850 us; speedup vs baseline: 1.4848x; 1.1289x over previous
//
#include <hip/hip_runtime.h>
#include <hip/hip_bf16.h>
#include <stdint.h>

#define B_   8
#define S_   1042
#define H_   768
#define NH_  12
#define HD_  64
#define MLP_ 2048
#define T_   (B_*S_)    // 8336 tokens
#define MP_  8448       // tokens padded to 66*128 (and 33*256)
#define SP_  1088       // seq padded to 17*64
#define EPS_ 1e-6f

typedef __attribute__((ext_vector_type(8))) short bf16x8v;
typedef __attribute__((ext_vector_type(4))) float f32x4;
typedef __hip_bfloat16 bf16;

typedef __attribute__((address_space(1))) const void gas_void;
typedef __attribute__((address_space(3))) void las_void;

__device__ inline void gload_lds16(const void* g, void* l) {
  __builtin_amdgcn_global_load_lds((gas_void*)g, (las_void*)l, 16, 0, 0);
}

#define BARRIER asm volatile("s_barrier" ::: "memory")
#define VMCNT4  asm volatile("s_waitcnt vmcnt(4)" ::: "memory")

// ---------------- weight convert + transpose (LDS-tiled): out[n*K+k] = W[k*N+n] ----------------
__global__ __launch_bounds__(256) void wcvt_t(const float* __restrict__ W, bf16* __restrict__ o,
                                              int K, int N) {
  __shared__ float tile[32][33];
  int kt = blockIdx.x, nt = blockIdx.y;
  int t = threadIdx.x;
  int r = t >> 5, c = t & 31;
#pragma unroll
  for (int i = 0; i < 4; i++)
    tile[i * 8 + r][c] = W[(long)(kt * 32 + i * 8 + r) * N + nt * 32 + c];
  __syncthreads();
#pragma unroll
  for (int i = 0; i < 4; i++)
    o[(long)(nt * 32 + i * 8 + r) * K + kt * 32 + c] = __float2bfloat16(tile[c][i * 8 + r]);
}

// ---------------- gate/up interleaved weight transpose ----------------
__global__ __launch_bounds__(256) void wcvt_gu(const float* __restrict__ Wg,
                                               const float* __restrict__ Wu,
                                               bf16* __restrict__ o) {
  __shared__ float tile[32][33];
  int kt = blockIdx.x, nt = blockIdx.y;   // k-tile (24), n-tile (128)
  int t = threadIdx.x;
  int r = t >> 5, c = t & 31;
  const float* src = (c < 16) ? Wg : Wu;
  int col = nt * 16 + (c & 15);
#pragma unroll
  for (int i = 0; i < 4; i++)
    tile[i * 8 + r][c] = src[(long)(kt * 32 + i * 8 + r) * MLP_ + col];
  __syncthreads();
#pragma unroll
  for (int i = 0; i < 4; i++)
    o[(long)(nt * 32 + i * 8 + r) * 768 + kt * 32 + c] = __float2bfloat16(tile[c][i * 8 + r]);
}

// ---------------- rmsnorm (768 wide), fp32 in -> bf16 out; GATE: fused head-gate ----------------
template <int GATE>
__global__ __launch_bounds__(256) void rmsnorm_k(const float* __restrict__ x,
                                                 const float* __restrict__ w,
                                                 bf16* __restrict__ o,
                                                 const float* __restrict__ gW,
                                                 const float* __restrict__ gb,
                                                 float* __restrict__ gate, int Mreal) {
  int row = blockIdx.x;
  bf16* orow = o + (long)row * H_;
  int t = threadIdx.x;
  if (row >= Mreal) {
    for (int i = t; i < H_; i += 256) orow[i] = __float2bfloat16(0.f);
    return;
  }
  const float* xr = x + (long)row * H_;
  float v0 = xr[t], v1 = xr[t + 256], v2 = xr[t + 512];
  float s = v0 * v0 + v1 * v1 + v2 * v2;
  for (int off = 32; off; off >>= 1) s += __shfl_down(s, off);
  __shared__ float red[4];
  __shared__ float gred[4][12];
  if ((t & 63) == 0) red[t >> 6] = s;
  __syncthreads();
  float tot = red[0] + red[1] + red[2] + red[3];
  float inv = rsqrtf(tot * (1.f / H_) + EPS_);
  float h0 = v0 * inv * w[t], h1 = v1 * inv * w[t + 256], h2 = v2 * inv * w[t + 512];
  orow[t]       = __float2bfloat16(h0);
  orow[t + 256] = __float2bfloat16(h1);
  orow[t + 512] = __float2bfloat16(h2);
  if (GATE) {
    const float* g0 = gW + (long)t * 12;
    const float* g1 = gW + (long)(t + 256) * 12;
    const float* g2 = gW + (long)(t + 512) * 12;
    float g[12];
#pragma unroll
    for (int n = 0; n < 12; n++) g[n] = h0 * g0[n] + h1 * g1[n] + h2 * g2[n];
#pragma unroll
    for (int n = 0; n < 12; n++) {
      float v = g[n];
      v += __shfl_xor(v, 1); v += __shfl_xor(v, 2); v += __shfl_xor(v, 4);
      v += __shfl_xor(v, 8); v += __shfl_xor(v, 16); v += __shfl_xor(v, 32);
      if ((t & 63) == 0) gred[t >> 6][n] = v;
    }
    __syncthreads();
    if (t < 12) {
      float s4 = gred[0][t] + gred[1][t] + gred[2][t] + gred[3][t];
      gate[(long)row * 12 + t] = 1.f / (1.f + __expf(-(s4 + gb[t])));
    }
  }
}

// ======== 256x256 8-phase GEMM, K=768 fixed, BK=64, 8 waves, hoisted addressing ========
// A (M x 768 row-major), Bt (N x 768 row-major). EPI 0: bf16 out (ld=N).
// EPI 2: silu-fused gate/up interleaved -> bf16 out ld=2048.
template <int EPI>
__global__ __launch_bounds__(512) void gemm256(
    const bf16* __restrict__ A, const bf16* __restrict__ Bt, void* __restrict__ Out,
    int N, int nbn) {
  // LDS: [buf][region: A-half0, A-half1, B-half0, B-half1][128 rows x 64 k]
  __shared__ __align__(16) bf16 lds[2][4][128 * 64];
  int tid = threadIdx.x;
  int lane = tid & 63, wid = tid >> 6;
  int wr = wid >> 2, wc = wid & 3;         // wave grid 2(M) x 4(N)
  int lr = lane & 15, lg = lane >> 4;

  // XCD-bijective block swizzle (m204)
  int nwg = gridDim.x;
  int bid = blockIdx.x;
  int q = nwg >> 3, r8 = nwg & 7;
  int xcd = bid & 7, idx = bid >> 3;
  int wg = (xcd < r8 ? xcd * (q + 1) : r8 * (q + 1) + (xcd - r8) * q) + idx;
  int bm = wg / nbn, bn = wg - bm * nbn;

  // --- hoisted ds-read base pointers: row&7 == lr&7 for every fragment row ---
  const bf16 *aP0[2], *aP1[2], *bP0[2], *bP1[2];
  {
    int off0 = lr * 64 + ((lg ^ (lr & 7)) * 8);
    int off1 = lr * 64 + (((4 + lg) ^ (lr & 7)) * 8);
#pragma unroll
    for (int b = 0; b < 2; b++) {
      aP0[b] = &lds[b][wr][off0];
      aP1[b] = &lds[b][wr][off1];
      bP0[b] = &lds[b][2 + (wc >> 1)][(wc & 1) * 4096 + off0];
      bP1[b] = &lds[b][2 + (wc >> 1)][(wc & 1) * 4096 + off1];
    }
  }
  // --- hoisted staging pointers (inverse-swizzled global source) ---
  int chunk_row = tid >> 3;                      // 0..63
  int cc = (tid & 7) ^ (chunk_row & 7);
  const bf16 *aB[2][2], *bB[2][2];
#pragma unroll
  for (int h = 0; h < 2; h++)
#pragma unroll
    for (int sub = 0; sub < 2; sub++) {
      aB[h][sub] = A + ((long)bm * 256 + h * 128 + sub * 64 + chunk_row) * 768 + cc * 8;
      bB[h][sub] = Bt + ((long)bn * 256 + h * 128 + sub * 64 + chunk_row) * 768 + cc * 8;
    }

#define STA(buf, half, kt)                                                      \
  {                                                                             \
    gload_lds16(aB[half][0] + (kt) * 64, &lds[buf][half][tid * 8]);             \
    gload_lds16(aB[half][1] + (kt) * 64, &lds[buf][half][4096 + tid * 8]);      \
  }
#define STB(buf, half, kt)                                                      \
  {                                                                             \
    gload_lds16(bB[half][0] + (kt) * 64, &lds[buf][2 + (half)][tid * 8]);       \
    gload_lds16(bB[half][1] + (kt) * 64, &lds[buf][2 + (half)][4096 + tid * 8]);\
  }

  f32x4 z; z[0] = z[1] = z[2] = z[3] = 0.f;
  f32x4 acc[8][4];
#pragma unroll
  for (int mi = 0; mi < 8; mi++)
#pragma unroll
    for (int ni = 0; ni < 4; ni++) acc[mi][ni] = z;

  bf16x8v bf[4][2];   // B frags for current tile (live across its 4 phases)
  bf16x8v af[4];      // A frags for current phase

  // prologue: tile0 full + tile1 B-halves
  STA(0, 0, 0); STA(0, 1, 0); STB(0, 0, 0); STB(0, 1, 0);
  STB(1, 0, 1); STB(1, 1, 1);
  VMCNT4;           // tile0 fully landed (leaves tile1 B in flight)
  BARRIER;

  // one barrier per phase; vmcnt after MFMA on phases 4/8 only
#define PHASE(p, bb, STG, VM)                                                   \
  {                                                                             \
    if ((p) == 0) {                                                             \
      _Pragma("unroll") for (int ni = 0; ni < 4; ni++) {                        \
        bf[ni][0] = *(const bf16x8v*)(bP0[bb] + ni * 1024);                     \
        bf[ni][1] = *(const bf16x8v*)(bP1[bb] + ni * 1024);                     \
      }                                                                         \
    }                                                                           \
    af[0] = *(const bf16x8v*)(aP0[bb] + (2 * (p)) * 1024);                      \
    af[1] = *(const bf16x8v*)(aP1[bb] + (2 * (p)) * 1024);                      \
    af[2] = *(const bf16x8v*)(aP0[bb] + (2 * (p) + 1) * 1024);                  \
    af[3] = *(const bf16x8v*)(aP1[bb] + (2 * (p) + 1) * 1024);                  \
    STG;                                                                        \
    BARRIER;                                                                    \
    __builtin_amdgcn_s_setprio(1);                                              \
    _Pragma("unroll") for (int dm = 0; dm < 2; dm++)                            \
      _Pragma("unroll") for (int ni = 0; ni < 4; ni++) {                        \
        acc[2 * (p) + dm][ni] = __builtin_amdgcn_mfma_f32_16x16x32_bf16(        \
            af[dm * 2 + 0], bf[ni][0], acc[2 * (p) + dm][ni], 0, 0, 0);         \
        acc[2 * (p) + dm][ni] = __builtin_amdgcn_mfma_f32_16x16x32_bf16(        \
            af[dm * 2 + 1], bf[ni][1], acc[2 * (p) + dm][ni], 0, 0, 0);         \
      }                                                                         \
    __builtin_amdgcn_s_setprio(0);                                              \
    if (VM) VMCNT4;                                                             \
  }

#pragma unroll
  for (int i = 0; i < 6; i++) {
    // tile 2i from buf0, staging per the race-free map (stages read garbage past K on last iter; never consumed)
    PHASE(0, 0, STA(1, 0, 2 * i + 1), 0);
    PHASE(1, 0, STA(1, 1, 2 * i + 1), 0);
    PHASE(2, 0, STB(0, 0, 2 * i + 2), 0);
    PHASE(3, 0, STB(0, 1, 2 * i + 2), 1);
    // tile 2i+1 from buf1
    PHASE(0, 1, STA(0, 0, 2 * i + 2), 0);
    PHASE(1, 1, STA(0, 1, 2 * i + 2), 0);
    PHASE(2, 1, STB(1, 0, 2 * i + 3), 0);
    PHASE(3, 1, STB(1, 1, 2 * i + 3), 1);
  }
#undef PHASE
#undef STA
#undef STB

  // epilogue
  long rowbase = (long)bm * 256 + wr * 128;
  int colbase = bn * 256 + wc * 64;
  if (EPI == 0) {
    bf16* O = (bf16*)Out;
#pragma unroll
    for (int mi = 0; mi < 8; mi++)
#pragma unroll
      for (int ni = 0; ni < 4; ni++)
#pragma unroll
        for (int r = 0; r < 4; r++)
          O[(rowbase + mi * 16 + lg * 4 + r) * N + colbase + ni * 16 + lr] =
              __float2bfloat16(acc[mi][ni][r]);
  } else {
    bf16* O = (bf16*)Out;
    int oc0 = colbase >> 1;
#pragma unroll
    for (int mi = 0; mi < 8; mi++)
#pragma unroll
      for (int p = 0; p < 2; p++)
#pragma unroll
        for (int r = 0; r < 4; r++) {
          float g = acc[mi][2 * p][r], u = acc[mi][2 * p + 1][r];
          float v = g / (1.f + __expf(-g)) * u;
          O[(rowbase + mi * 16 + lg * 4 + r) * 2048 + oc0 + p * 16 + lr] =
              __float2bfloat16(v);
        }
  }
}

// ---------------- old 128x128 GEMM (kept for Wo / MLP2): EPI1 fp32 resid+scale ----------------
template <int EPI>
__global__ __launch_bounds__(256) void gemm_bf16(
    const bf16* __restrict__ A, const bf16* __restrict__ Bt, void* __restrict__ Out,
    const float* __restrict__ resid, const float* __restrict__ scale,
    int N, int K, int Mreal) {
  __shared__ __align__(16) bf16 As[128 * 32];
  __shared__ __align__(16) bf16 Bs[128 * 32];
  int tid = threadIdx.x;
  int lane = tid & 63, wid = tid >> 6;
  int wm = wid >> 1, wn = wid & 1;
  int lr = lane & 15, lg = lane >> 4;
  long rowA0 = (long)blockIdx.y * 128;
  long rowB0 = (long)blockIdx.x * 128;
  f32x4 z; z[0] = z[1] = z[2] = z[3] = 0.f;
  f32x4 acc[4][4];
#pragma unroll
  for (int mi = 0; mi < 4; mi++)
#pragma unroll
    for (int ni = 0; ni < 4; ni++) acc[mi][ni] = z;

  const int flat0 = wid * 512 + lane * 8;
  const bf16* Ab = A + rowA0 * K;
  const bf16* Bb = Bt + rowB0 * K;

  for (int k0 = 0; k0 < K; k0 += 32) {
    __syncthreads();
#pragma unroll
    for (int j = 0; j < 2; j++) {
      int flat = flat0 + j * 2048;
      int r = flat >> 5, c = flat & 31;
      gload_lds16(Ab + (long)r * K + k0 + c, &As[flat]);
      gload_lds16(Bb + (long)r * K + k0 + c, &Bs[flat]);
    }
    __syncthreads();
    bf16x8v af[4], bfr[4];
#pragma unroll
    for (int mi = 0; mi < 4; mi++)
      af[mi] = *(const bf16x8v*)&As[(wm * 64 + mi * 16 + lr) * 32 + lg * 8];
#pragma unroll
    for (int ni = 0; ni < 4; ni++)
      bfr[ni] = *(const bf16x8v*)&Bs[(wn * 64 + ni * 16 + lr) * 32 + lg * 8];
#pragma unroll
    for (int mi = 0; mi < 4; mi++)
#pragma unroll
      for (int ni = 0; ni < 4; ni++)
        acc[mi][ni] = __builtin_amdgcn_mfma_f32_16x16x32_bf16(af[mi], bfr[ni], acc[mi][ni], 0, 0, 0);
  }

#pragma unroll
  for (int mi = 0; mi < 4; mi++) {
#pragma unroll
    for (int ni = 0; ni < 4; ni++) {
#pragma unroll
      for (int r = 0; r < 4; r++) {
        long row = rowA0 + wm * 64 + mi * 16 + lg * 4 + r;
        long col = rowB0 + wn * 64 + ni * 16 + lr;
        float v = acc[mi][ni][r];
        if (EPI == 0) {
          ((bf16*)Out)[row * N + col] = __float2bfloat16(v);
        } else {
          if (row < Mreal)
            ((float*)Out)[row * N + col] = resid[row * N + col] + v * scale[col];
        }
      }
    }
  }
}

// ---------------- V transpose: qkv v-part -> vtf[(bh*64+d)*SP_+s] ----------------
__global__ __launch_bounds__(256) void vtran(const bf16* __restrict__ qkv, bf16* __restrict__ vtf) {
  __shared__ bf16 tile[32][66];
  int st = blockIdx.x, bh = blockIdx.y;
  int bb = bh / NH_, h = bh - bb * NH_;
  int s0 = st * 32;
  int t = threadIdx.x;
  int si = t >> 6, d = t & 63;
#pragma unroll
  for (int i = 0; i < 8; i++) {
    int s = s0 + i * 4 + si;
    bf16 v = __float2bfloat16(0.f);
    if (s < S_) v = qkv[(long)(bb * S_ + s) * 2304 + 1536 + h * 64 + d];
    tile[i * 4 + si][d] = v;
  }
  __syncthreads();
  int dd = t >> 5, sj = t & 31;
#pragma unroll
  for (int i = 0; i < 8; i++) {
    int d2 = i * 8 + dd;
    vtf[((long)bh * 64 + d2) * SP_ + s0 + sj] = tile[sj][d2];
  }
}

// ---------------- qk rmsnorm + rope + scale (q scaled to base-2 exp units) ----------------
__global__ __launch_bounds__(768) void qkv_post(
    const bf16* __restrict__ qkv, const float* __restrict__ qw, const float* __restrict__ kw,
    const float* __restrict__ cosT, const float* __restrict__ sinT,
    bf16* __restrict__ qf, bf16* __restrict__ kf) {
  int tok = blockIdx.x;
  int bb = tok / S_, s = tok - bb * S_;
  int h = threadIdx.x >> 6, d = threadIdx.x & 63;
  const bf16* base = qkv + (long)tok * 2304 + h * 64 + d;
  float q = __bfloat162float(base[0]);
  float k = __bfloat162float(base[768]);
  float qs = q * q, ks = k * k;
  for (int off = 32; off; off >>= 1) {
    qs += __shfl_xor(qs, off);
    ks += __shfl_xor(ks, off);
  }
  q *= rsqrtf(qs * (1.f / 64.f) + EPS_) * qw[d];
  k *= rsqrtf(ks * (1.f / 64.f) + EPS_) * kw[d];
  if (s >= S_ - 1024) {
    int pos = s - (S_ - 1024);
    int i = d >> 1;
    float c = cosT[pos * 32 + i], sn = sinT[pos * 32 + i];
    float qp = __shfl_xor(q, 1), kp = __shfl_xor(k, 1);
    if (d & 1) { q = qp * sn + q * c; k = kp * sn + k * c; }
    else       { q = q * c - qp * sn; k = k * c - kp * sn; }
  }
  q *= 0.125f * 1.44269504088896f;  // fold log2(e): softmax done in base 2
  long o1 = ((long)(bb * NH_ + h) * SP_ + s) * 64 + d;
  qf[o1] = __float2bfloat16(q);
  kf[o1] = __float2bfloat16(k);
}

// swizzled LDS element offset for a [64][8x(8elem)] bf16 tile: row, colchunk cc
#define SWZ(row, cc) (((row) << 6) + ((((cc) ^ ((row) & 7))) << 3))

// ---------------- flash attention: 4 waves/block, 64 q-rows, LDS dbuf K/V ----------------
__global__ __launch_bounds__(256) void attn_k(
    const bf16* __restrict__ qf, const bf16* __restrict__ kf, const bf16* __restrict__ vtf,
    const float* __restrict__ gate, bf16* __restrict__ attn_g) {
  __shared__ __align__(16) bf16 Ks[2][64 * 64];
  __shared__ __align__(16) bf16 Vs[2][64 * 64];
  int bid = blockIdx.x;                      // 1632 = 8 * 204
  int w = (bid & 7) * 204 + (bid >> 3);      // XCD-pinned: 12 bh per XCD
  int bh = w / 17, qb = w - bh * 17;
  int bb = bh / NH_, h = bh - bb * NH_;
  int tid = threadIdx.x;
  int lane = tid & 63, wv = tid >> 6;
  int lr = lane & 15, lg = lane >> 4;
  const bf16* qbase = qf + (long)bh * SP_ * 64;
  const bf16* kbase = kf + (long)bh * SP_ * 64;
  const bf16* vbase = vtf + (long)bh * 64 * SP_;

  int q_l = qb * 64 + wv * 16 + lr;          // q row this lane owns (softmax state)
  bf16x8v qB0 = *(const bf16x8v*)(qbase + (long)q_l * 64 + lg * 8);
  bf16x8v qB1 = *(const bf16x8v*)(qbase + (long)q_l * 64 + 32 + lg * 8);

  f32x4 z; z[0] = z[1] = z[2] = z[3] = 0.f;
  f32x4 acc[4] = {z, z, z, z};
  float m = -1e30f, lsum = 0.f;

  auto stage = [&](int buf, int kidx) {
#pragma unroll
    for (int inst = 0; inst < 2; inst++) {
      int c = inst * 256 + tid;
      int row = c >> 3, slot = c & 7;
      int cc = slot ^ (row & 7);
      gload_lds16(kbase + (long)(kidx + row) * 64 + cc * 8, &Ks[buf][c * 8]);
    }
#pragma unroll
    for (int inst = 0; inst < 2; inst++) {
      int c = inst * 256 + tid;
      int row = c >> 3, slot = c & 7;
      int cc = slot ^ (row & 7);
      gload_lds16(vbase + (long)row * SP_ + kidx + cc * 8, &Vs[buf][c * 8]);
    }
  };

  stage(0, 0);
  asm volatile("s_waitcnt vmcnt(0)" ::: "memory");
  __syncthreads();
  int cur = 0;

  for (int kt = 0; kt < SP_ / 64; kt++) {
    int kidx = kt * 64;
    if (kt < SP_ / 64 - 1) stage(cur ^ 1, kidx + 64);

    f32x4 p[4];
    __builtin_amdgcn_s_setprio(1);
#pragma unroll
    for (int mt = 0; mt < 4; mt++) {
      int row = mt * 16 + lr;
      bf16x8v k0 = *(const bf16x8v*)&Ks[cur][SWZ(row, lg)];
      bf16x8v k1 = *(const bf16x8v*)&Ks[cur][SWZ(row, lg + 4)];
      f32x4 t = z;
      t = __builtin_amdgcn_mfma_f32_16x16x32_bf16(k0, qB0, t, 0, 0, 0);
      t = __builtin_amdgcn_mfma_f32_16x16x32_bf16(k1, qB1, t, 0, 0, 0);
      p[mt] = t;
    }
    __builtin_amdgcn_s_setprio(0);

    if (kidx + 64 > S_) {
#pragma unroll
      for (int mt = 0; mt < 4; mt++)
#pragma unroll
        for (int r = 0; r < 4; r++)
          if (kidx + mt * 16 + lg * 4 + r >= S_) p[mt][r] = -1e30f;
    }

    float tmax = p[0][0];
#pragma unroll
    for (int mt = 0; mt < 4; mt++)
#pragma unroll
      for (int r = 0; r < 4; r++) tmax = fmaxf(tmax, p[mt][r]);
    tmax = fmaxf(tmax, __shfl_xor(tmax, 16));
    tmax = fmaxf(tmax, __shfl_xor(tmax, 32));

    if (__ballot(tmax > m + 11.0f)) {
      float mn = fmaxf(m, tmax);
      float so = exp2f(m - mn);
      m = mn;
      lsum *= so;
      float so4[4];
#pragma unroll
      for (int r = 0; r < 4; r++) so4[r] = __shfl(so, lg * 4 + r);
#pragma unroll
      for (int dt = 0; dt < 4; dt++) {
        f32x4 a = acc[dt];
        a[0] *= so4[0]; a[1] *= so4[1]; a[2] *= so4[2]; a[3] *= so4[3];
        acc[dt] = a;
      }
    }
    float ts = 0.f;
#pragma unroll
    for (int mt = 0; mt < 4; mt++)
#pragma unroll
      for (int r = 0; r < 4; r++) {
        float e = exp2f(p[mt][r] - m);
        p[mt][r] = e;
        ts += e;
      }
    ts += __shfl_xor(ts, 16);
    ts += __shfl_xor(ts, 32);
    lsum += ts;

    uint32_t w0[4], w1[4];
#pragma unroll
    for (int mt = 0; mt < 4; mt++) {
      asm("v_cvt_pk_bf16_f32 %0, %1, %2" : "=v"(w0[mt]) : "v"(p[mt][0]), "v"(p[mt][1]));
      asm("v_cvt_pk_bf16_f32 %0, %1, %2" : "=v"(w1[mt]) : "v"(p[mt][2]), "v"(p[mt][3]));
    }
    bf16x8v aP[2];
#pragma unroll
    for (int t2 = 0; t2 < 2; t2++) {
      union { uint32_t u[4]; bf16x8v v; } cvt;
#pragma unroll
      for (int wd = 0; wd < 4; wd++) {
        uint32_t a = (wd & 1) ? w1[2 * t2] : w0[2 * t2];
        uint32_t b = (wd & 1) ? w1[2 * t2 + 1] : w0[2 * t2 + 1];
        uint32_t val = (lg & 2) ? b : a;
        int src = ((lg & 1) * 2 + (wd >> 1)) * 16 + lr;
        cvt.u[wd] = (uint32_t)__shfl((int)val, src);
      }
      aP[t2] = cvt.v;
    }
    __builtin_amdgcn_s_setprio(1);
#pragma unroll
    for (int t2 = 0; t2 < 2; t2++)
#pragma unroll
      for (int dt = 0; dt < 4; dt++) {
        int row = dt * 16 + lr;
        bf16x8v vB = *(const bf16x8v*)&Vs[cur][SWZ(row, t2 * 4 + lg)];
        acc[dt] = __builtin_amdgcn_mfma_f32_16x16x32_bf16(aP[t2], vB, acc[dt], 0, 0, 0);
      }
    __builtin_amdgcn_s_setprio(0);

    asm volatile("s_waitcnt vmcnt(0)" ::: "memory");
    __syncthreads();
    cur ^= 1;
  }

  float norm = 0.f;
  if (q_l < S_) norm = gate[((long)bb * S_ + q_l) * 12 + h] / lsum;
  float nr[4];
#pragma unroll
  for (int r = 0; r < 4; r++) nr[r] = __shfl(norm, lg * 4 + r);
#pragma unroll
  for (int dt = 0; dt < 4; dt++)
#pragma unroll
    for (int r = 0; r < 4; r++) {
      int qr = qb * 64 + wv * 16 + lg * 4 + r;
      if (qr < S_)
        attn_g[((long)bb * S_ + qr) * H_ + h * 64 + dt * 16 + lr] =
            __float2bfloat16(acc[dt][r] * nr[r]);
    }
}

extern "C" void kernel_launch(void* const* d_in, const int* in_sizes, int n_in,
                              void* d_out, int out_size, void* d_ws, size_t ws_size,
                              hipStream_t stream) {
  const float* x    = (const float*)d_in[0];
  const float* cosT = (const float*)d_in[1];
  const float* sinT = (const float*)d_in[2];
  const float* Wq   = (const float*)d_in[3];
  const float* Wk   = (const float*)d_in[4];
  const float* Wv   = (const float*)d_in[5];
  const float* Wo   = (const float*)d_in[6];
  const float* qnw  = (const float*)d_in[7];
  const float* knw  = (const float*)d_in[8];
  const float* gW   = (const float*)d_in[9];
  const float* gb   = (const float*)d_in[10];
  const float* n1w  = (const float*)d_in[11];
  const float* n2w  = (const float*)d_in[12];
  const float* Wg   = (const float*)d_in[13];
  const float* Wu   = (const float*)d_in[14];
  const float* Wd   = (const float*)d_in[15];
  const float* ascale = (const float*)d_in[16];
  const float* mscale = (const float*)d_in[17];

  char* ws = (char*)d_ws;
  size_t off = 0;
  auto alloc = [&](size_t bytes) {
    char* p = ws + off;
    off += (bytes + 255) & ~(size_t)255;
    return p;
  };
  bf16* h_pad  = (bf16*)alloc((size_t)MP_ * H_ * 2);      // reused as h2
  bf16* wqkv_t = (bf16*)alloc((size_t)2304 * 768 * 2);
  bf16* wo_t   = (bf16*)alloc((size_t)768 * 768 * 2);
  bf16* wgu_t  = (bf16*)alloc((size_t)4096 * 768 * 2);    // gate/up 16-col interleaved
  bf16* wdn_t  = (bf16*)alloc((size_t)768 * 2048 * 2);
  bf16* qkv    = (bf16*)alloc((size_t)MP_ * 2304 * 2);    // reused as mlpin (MP_*2048)
  bf16* qfb    = (bf16*)alloc((size_t)96 * SP_ * 64 * 2);
  bf16* kfb    = (bf16*)alloc((size_t)96 * SP_ * 64 * 2);
  bf16* vtfb   = (bf16*)alloc((size_t)96 * SP_ * 64 * 2);
  float* gateb = (float*)alloc((size_t)T_ * 12 * 4);
  bf16* attn_g = (bf16*)alloc((size_t)MP_ * H_ * 2);
  float* x2    = (float*)alloc((size_t)T_ * H_ * 4);
  bf16* mlpin  = qkv;

  // weight conversion
  auto wc = [&](const float* W, bf16* o, int K, int N) {
    wcvt_t<<<dim3(K / 32, N / 32), 256, 0, stream>>>(W, o, K, N);
  };
  wc(Wq, wqkv_t, 768, 768);
  wc(Wk, wqkv_t + 768 * 768, 768, 768);
  wc(Wv, wqkv_t + 2 * 768 * 768, 768, 768);
  wc(Wo, wo_t, 768, 768);
  wc(Wd, wdn_t, 2048, 768);
  wcvt_gu<<<dim3(24, 128), 256, 0, stream>>>(Wg, Wu, wgu_t);

  rmsnorm_k<1><<<MP_, 256, 0, stream>>>(x, n1w, h_pad, gW, gb, gateb, T_);

  gemm256<0><<<9 * 33, 512, 0, stream>>>(h_pad, wqkv_t, qkv, 2304, 9);

  qkv_post<<<T_, 768, 0, stream>>>(qkv, qnw, knw, cosT, sinT, qfb, kfb);
  vtran<<<dim3(33, 96), 256, 0, stream>>>(qkv, vtfb);

  attn_k<<<1632, 256, 0, stream>>>(qfb, kfb, vtfb, gateb, attn_g);

  gemm_bf16<1><<<dim3(768 / 128, MP_ / 128), 256, 0, stream>>>(
      attn_g, wo_t, x2, x, ascale, 768, 768, T_);

  rmsnorm_k<0><<<MP_, 256, 0, stream>>>(x2, n2w, h_pad, nullptr, nullptr, nullptr, T_);

  gemm256<2><<<16 * 33, 512, 0, stream>>>(h_pad, wgu_t, mlpin, 4096, 16);

  gemm_bf16<1><<<dim3(768 / 128, MP_ / 128), 256, 0, stream>>>(
      mlpin, wdn_t, (float*)d_out, x2, mscale, 768, 2048, T_);
}

// Round 8
// 407.165 us; speedup vs baseline: 1.5128x; 1.0189x over previous
//
#include <hip/hip_runtime.h>
#include <hip/hip_bf16.h>
#include <stdint.h>

#define B_   8
#define S_   1042
#define H_   768
#define NH_  12
#define HD_  64
#define MLP_ 2048
#define T_   (B_*S_)    // 8336 tokens
#define MP_  8448       // tokens padded to 66*128 (and 33*256)
#define SP_  1088       // seq padded to 17*64
#define EPS_ 1e-6f

typedef __attribute__((ext_vector_type(8))) short bf16x8v;
typedef __attribute__((ext_vector_type(4))) float f32x4;
typedef __hip_bfloat16 bf16;

typedef __attribute__((address_space(1))) const void gas_void;
typedef __attribute__((address_space(3))) void las_void;

__device__ inline void gload_lds16(const void* g, void* l) {
  __builtin_amdgcn_global_load_lds((gas_void*)g, (las_void*)l, 16, 0, 0);
}

#define BARRIER asm volatile("s_barrier" ::: "memory")
#define VMCNT4  asm volatile("s_waitcnt vmcnt(4)" ::: "memory")
#define VMCNT0  asm volatile("s_waitcnt vmcnt(0)" ::: "memory")

// ---------------- weight convert + transpose (LDS-tiled): out[n*K+k] = W[k*N+n] ----------------
__global__ __launch_bounds__(256) void wcvt_t(const float* __restrict__ W, bf16* __restrict__ o,
                                              int K, int N) {
  __shared__ float tile[32][33];
  int kt = blockIdx.x, nt = blockIdx.y;
  int t = threadIdx.x;
  int r = t >> 5, c = t & 31;
#pragma unroll
  for (int i = 0; i < 4; i++)
    tile[i * 8 + r][c] = W[(long)(kt * 32 + i * 8 + r) * N + nt * 32 + c];
  __syncthreads();
#pragma unroll
  for (int i = 0; i < 4; i++)
    o[(long)(nt * 32 + i * 8 + r) * K + kt * 32 + c] = __float2bfloat16(tile[c][i * 8 + r]);
}

// ---------------- gate/up interleaved weight transpose ----------------
__global__ __launch_bounds__(256) void wcvt_gu(const float* __restrict__ Wg,
                                               const float* __restrict__ Wu,
                                               bf16* __restrict__ o) {
  __shared__ float tile[32][33];
  int kt = blockIdx.x, nt = blockIdx.y;   // k-tile (24), n-tile (128)
  int t = threadIdx.x;
  int r = t >> 5, c = t & 31;
  const float* src = (c < 16) ? Wg : Wu;
  int col = nt * 16 + (c & 15);
#pragma unroll
  for (int i = 0; i < 4; i++)
    tile[i * 8 + r][c] = src[(long)(kt * 32 + i * 8 + r) * MLP_ + col];
  __syncthreads();
#pragma unroll
  for (int i = 0; i < 4; i++)
    o[(long)(nt * 32 + i * 8 + r) * 768 + kt * 32 + c] = __float2bfloat16(tile[c][i * 8 + r]);
}

// ---------------- rmsnorm (768 wide), fp32 in -> bf16 out; GATE: fused head-gate ----------------
template <int GATE>
__global__ __launch_bounds__(256) void rmsnorm_k(const float* __restrict__ x,
                                                 const float* __restrict__ w,
                                                 bf16* __restrict__ o,
                                                 const float* __restrict__ gW,
                                                 const float* __restrict__ gb,
                                                 float* __restrict__ gate, int Mreal) {
  int row = blockIdx.x;
  bf16* orow = o + (long)row * H_;
  int t = threadIdx.x;
  if (row >= Mreal) {
    for (int i = t; i < H_; i += 256) orow[i] = __float2bfloat16(0.f);
    return;
  }
  const float* xr = x + (long)row * H_;
  float v0 = xr[t], v1 = xr[t + 256], v2 = xr[t + 512];
  float s = v0 * v0 + v1 * v1 + v2 * v2;
  for (int off = 32; off; off >>= 1) s += __shfl_down(s, off);
  __shared__ float red[4];
  __shared__ float gred[4][12];
  if ((t & 63) == 0) red[t >> 6] = s;
  __syncthreads();
  float tot = red[0] + red[1] + red[2] + red[3];
  float inv = rsqrtf(tot * (1.f / H_) + EPS_);
  float h0 = v0 * inv * w[t], h1 = v1 * inv * w[t + 256], h2 = v2 * inv * w[t + 512];
  orow[t]       = __float2bfloat16(h0);
  orow[t + 256] = __float2bfloat16(h1);
  orow[t + 512] = __float2bfloat16(h2);
  if (GATE) {
    const float* g0 = gW + (long)t * 12;
    const float* g1 = gW + (long)(t + 256) * 12;
    const float* g2 = gW + (long)(t + 512) * 12;
    float g[12];
#pragma unroll
    for (int n = 0; n < 12; n++) g[n] = h0 * g0[n] + h1 * g1[n] + h2 * g2[n];
#pragma unroll
    for (int n = 0; n < 12; n++) {
      float v = g[n];
      v += __shfl_xor(v, 1); v += __shfl_xor(v, 2); v += __shfl_xor(v, 4);
      v += __shfl_xor(v, 8); v += __shfl_xor(v, 16); v += __shfl_xor(v, 32);
      if ((t & 63) == 0) gred[t >> 6][n] = v;
    }
    __syncthreads();
    if (t < 12) {
      float s4 = gred[0][t] + gred[1][t] + gred[2][t] + gred[3][t];
      gate[(long)row * 12 + t] = 1.f / (1.f + __expf(-(s4 + gb[t])));
    }
  }
}

// ======== 256x256 8-phase GEMM, K=768 fixed, BK=64, 8 waves (round-5 proven form) ========
// A (M x 768 row-major), Bt (N x 768 row-major). EPI 0: bf16 out (ld=N).
// EPI 2: silu-fused gate/up interleaved -> bf16 out ld=2048.
template <int EPI>
__global__ __launch_bounds__(512) void gemm256(
    const bf16* __restrict__ A, const bf16* __restrict__ Bt, void* __restrict__ Out,
    int N, int nbn) {
  __shared__ __align__(16) bf16 lds[2][4][128 * 64];
  int tid = threadIdx.x;
  int lane = tid & 63, wid = tid >> 6;
  int wr = wid >> 2, wc = wid & 3;         // wave grid 2(M) x 4(N)
  int lr = lane & 15, lg = lane >> 4;

  // XCD-bijective block swizzle (m204)
  int nwg = gridDim.x;
  int bid = blockIdx.x;
  int q = nwg >> 3, r8 = nwg & 7;
  int xcd = bid & 7, idx = bid >> 3;
  int wg = (xcd < r8 ? xcd * (q + 1) : r8 * (q + 1) + (xcd - r8) * q) + idx;
  int bm = wg / nbn, bn = wg - bm * nbn;

  // hoisted ds-read base pointers: row&7 == lr&7 for every fragment row
  const bf16 *aP0[2], *aP1[2], *bP0[2], *bP1[2];
  {
    int off0 = lr * 64 + ((lg ^ (lr & 7)) * 8);
    int off1 = lr * 64 + (((4 + lg) ^ (lr & 7)) * 8);
#pragma unroll
    for (int b = 0; b < 2; b++) {
      aP0[b] = &lds[b][wr][off0];
      aP1[b] = &lds[b][wr][off1];
      bP0[b] = &lds[b][2 + (wc >> 1)][(wc & 1) * 4096 + off0];
      bP1[b] = &lds[b][2 + (wc >> 1)][(wc & 1) * 4096 + off1];
    }
  }
  // hoisted staging pointers (inverse-swizzled global source)
  int chunk_row = tid >> 3;                      // 0..63
  int cc = (tid & 7) ^ (chunk_row & 7);
  const bf16 *aB[2][2], *bB[2][2];
#pragma unroll
  for (int h = 0; h < 2; h++)
#pragma unroll
    for (int sub = 0; sub < 2; sub++) {
      aB[h][sub] = A + ((long)bm * 256 + h * 128 + sub * 64 + chunk_row) * 768 + cc * 8;
      bB[h][sub] = Bt + ((long)bn * 256 + h * 128 + sub * 64 + chunk_row) * 768 + cc * 8;
    }

#define STA(buf, half, kt)                                                      \
  {                                                                             \
    gload_lds16(aB[half][0] + (kt) * 64, &lds[buf][half][tid * 8]);             \
    gload_lds16(aB[half][1] + (kt) * 64, &lds[buf][half][4096 + tid * 8]);      \
  }
#define STB(buf, half, kt)                                                      \
  {                                                                             \
    gload_lds16(bB[half][0] + (kt) * 64, &lds[buf][2 + (half)][tid * 8]);       \
    gload_lds16(bB[half][1] + (kt) * 64, &lds[buf][2 + (half)][4096 + tid * 8]);\
  }

  f32x4 z; z[0] = z[1] = z[2] = z[3] = 0.f;
  f32x4 acc[8][4];
#pragma unroll
  for (int mi = 0; mi < 8; mi++)
#pragma unroll
    for (int ni = 0; ni < 4; ni++) acc[mi][ni] = z;

  bf16x8v bf[4][2];
  bf16x8v af[4];

  // prologue: tile0 full + tile1 B-halves
  STA(0, 0, 0); STA(0, 1, 0); STB(0, 0, 0); STB(0, 1, 0);
  STB(1, 0, 1); STB(1, 1, 1);
  VMCNT4;
  BARRIER;

#define PHASE(p, bb, STG, VM)                                                   \
  {                                                                             \
    if ((p) == 0) {                                                             \
      _Pragma("unroll") for (int ni = 0; ni < 4; ni++) {                        \
        bf[ni][0] = *(const bf16x8v*)(bP0[bb] + ni * 1024);                     \
        bf[ni][1] = *(const bf16x8v*)(bP1[bb] + ni * 1024);                     \
      }                                                                         \
    }                                                                           \
    af[0] = *(const bf16x8v*)(aP0[bb] + (2 * (p)) * 1024);                      \
    af[1] = *(const bf16x8v*)(aP1[bb] + (2 * (p)) * 1024);                      \
    af[2] = *(const bf16x8v*)(aP0[bb] + (2 * (p) + 1) * 1024);                  \
    af[3] = *(const bf16x8v*)(aP1[bb] + (2 * (p) + 1) * 1024);                  \
    STG;                                                                        \
    BARRIER;                                                                    \
    __builtin_amdgcn_s_setprio(1);                                              \
    _Pragma("unroll") for (int dm = 0; dm < 2; dm++)                            \
      _Pragma("unroll") for (int ni = 0; ni < 4; ni++) {                        \
        acc[2 * (p) + dm][ni] = __builtin_amdgcn_mfma_f32_16x16x32_bf16(        \
            af[dm * 2 + 0], bf[ni][0], acc[2 * (p) + dm][ni], 0, 0, 0);         \
        acc[2 * (p) + dm][ni] = __builtin_amdgcn_mfma_f32_16x16x32_bf16(        \
            af[dm * 2 + 1], bf[ni][1], acc[2 * (p) + dm][ni], 0, 0, 0);         \
      }                                                                         \
    __builtin_amdgcn_s_setprio(0);                                              \
    if (VM) VMCNT4;                                                             \
  }

#pragma unroll
  for (int i = 0; i < 6; i++) {
    int u = 2 * i + 1;
    int t2 = (2 * i + 2 < 12) ? 2 * i + 2 : 11;
    int t3 = (2 * i + 3 < 12) ? 2 * i + 3 : 11;
    PHASE(0, 0, STA(1, 0, u), 0);
    PHASE(1, 0, STA(1, 1, u), 0);
    PHASE(2, 0, STB(0, 0, t2), 0);
    PHASE(3, 0, STB(0, 1, t2), 1);
    PHASE(0, 1, STA(0, 0, t2), 0);
    PHASE(1, 1, STA(0, 1, t2), 0);
    PHASE(2, 1, STB(1, 0, t3), 0);
    PHASE(3, 1, STB(1, 1, t3), 1);
  }
#undef PHASE
#undef STA
#undef STB

  // epilogue
  long rowbase = (long)bm * 256 + wr * 128;
  int colbase = bn * 256 + wc * 64;
  if (EPI == 0) {
    bf16* O = (bf16*)Out;
#pragma unroll
    for (int mi = 0; mi < 8; mi++)
#pragma unroll
      for (int ni = 0; ni < 4; ni++)
#pragma unroll
        for (int r = 0; r < 4; r++)
          O[(rowbase + mi * 16 + lg * 4 + r) * N + colbase + ni * 16 + lr] =
              __float2bfloat16(acc[mi][ni][r]);
  } else {
    bf16* O = (bf16*)Out;
    int oc0 = colbase >> 1;
#pragma unroll
    for (int mi = 0; mi < 8; mi++)
#pragma unroll
      for (int p = 0; p < 2; p++)
#pragma unroll
        for (int r = 0; r < 4; r++) {
          float g = acc[mi][2 * p][r], u = acc[mi][2 * p + 1][r];
          float v = g / (1.f + __expf(-g)) * u;
          O[(rowbase + mi * 16 + lg * 4 + r) * 2048 + oc0 + p * 16 + lr] =
              __float2bfloat16(v);
        }
  }
}

// ---------------- old 128x128 GEMM (Wo / MLP2): EPI1 fp32 resid+scale ----------------
template <int EPI>
__global__ __launch_bounds__(256) void gemm_bf16(
    const bf16* __restrict__ A, const bf16* __restrict__ Bt, void* __restrict__ Out,
    const float* __restrict__ resid, const float* __restrict__ scale,
    int N, int K, int Mreal) {
  __shared__ __align__(16) bf16 As[128 * 32];
  __shared__ __align__(16) bf16 Bs[128 * 32];
  int tid = threadIdx.x;
  int lane = tid & 63, wid = tid >> 6;
  int wm = wid >> 1, wn = wid & 1;
  int lr = lane & 15, lg = lane >> 4;
  long rowA0 = (long)blockIdx.y * 128;
  long rowB0 = (long)blockIdx.x * 128;
  f32x4 z; z[0] = z[1] = z[2] = z[3] = 0.f;
  f32x4 acc[4][4];
#pragma unroll
  for (int mi = 0; mi < 4; mi++)
#pragma unroll
    for (int ni = 0; ni < 4; ni++) acc[mi][ni] = z;

  const int flat0 = wid * 512 + lane * 8;
  const bf16* Ab = A + rowA0 * K;
  const bf16* Bb = Bt + rowB0 * K;

  for (int k0 = 0; k0 < K; k0 += 32) {
    __syncthreads();
#pragma unroll
    for (int j = 0; j < 2; j++) {
      int flat = flat0 + j * 2048;
      int r = flat >> 5, c = flat & 31;
      gload_lds16(Ab + (long)r * K + k0 + c, &As[flat]);
      gload_lds16(Bb + (long)r * K + k0 + c, &Bs[flat]);
    }
    __syncthreads();
    bf16x8v af[4], bfr[4];
#pragma unroll
    for (int mi = 0; mi < 4; mi++)
      af[mi] = *(const bf16x8v*)&As[(wm * 64 + mi * 16 + lr) * 32 + lg * 8];
#pragma unroll
    for (int ni = 0; ni < 4; ni++)
      bfr[ni] = *(const bf16x8v*)&Bs[(wn * 64 + ni * 16 + lr) * 32 + lg * 8];
#pragma unroll
    for (int mi = 0; mi < 4; mi++)
#pragma unroll
      for (int ni = 0; ni < 4; ni++)
        acc[mi][ni] = __builtin_amdgcn_mfma_f32_16x16x32_bf16(af[mi], bfr[ni], acc[mi][ni], 0, 0, 0);
  }

#pragma unroll
  for (int mi = 0; mi < 4; mi++) {
#pragma unroll
    for (int ni = 0; ni < 4; ni++) {
#pragma unroll
      for (int r = 0; r < 4; r++) {
        long row = rowA0 + wm * 64 + mi * 16 + lg * 4 + r;
        long col = rowB0 + wn * 64 + ni * 16 + lr;
        float v = acc[mi][ni][r];
        if (EPI == 0) {
          ((bf16*)Out)[row * N + col] = __float2bfloat16(v);
        } else {
          if (row < Mreal)
            ((float*)Out)[row * N + col] = resid[row * N + col] + v * scale[col];
        }
      }
    }
  }
}

// ---------------- V transpose: qkv v-part -> vtf[(bh*64+d)*SP_+s] ----------------
__global__ __launch_bounds__(256) void vtran(const bf16* __restrict__ qkv, bf16* __restrict__ vtf) {
  __shared__ bf16 tile[32][66];
  int st = blockIdx.x, bh = blockIdx.y;
  int bb = bh / NH_, h = bh - bb * NH_;
  int s0 = st * 32;
  int t = threadIdx.x;
  int si = t >> 6, d = t & 63;
#pragma unroll
  for (int i = 0; i < 8; i++) {
    int s = s0 + i * 4 + si;
    bf16 v = __float2bfloat16(0.f);
    if (s < S_) v = qkv[(long)(bb * S_ + s) * 2304 + 1536 + h * 64 + d];
    tile[i * 4 + si][d] = v;
  }
  __syncthreads();
  int dd = t >> 5, sj = t & 31;
#pragma unroll
  for (int i = 0; i < 8; i++) {
    int d2 = i * 8 + dd;
    vtf[((long)bh * 64 + d2) * SP_ + s0 + sj] = tile[sj][d2];
  }
}

// ---------------- qk rmsnorm + rope + scale (q scaled to base-2 exp units) ----------------
__global__ __launch_bounds__(768) void qkv_post(
    const bf16* __restrict__ qkv, const float* __restrict__ qw, const float* __restrict__ kw,
    const float* __restrict__ cosT, const float* __restrict__ sinT,
    bf16* __restrict__ qf, bf16* __restrict__ kf) {
  int tok = blockIdx.x;
  int bb = tok / S_, s = tok - bb * S_;
  int h = threadIdx.x >> 6, d = threadIdx.x & 63;
  const bf16* base = qkv + (long)tok * 2304 + h * 64 + d;
  float q = __bfloat162float(base[0]);
  float k = __bfloat162float(base[768]);
  float qs = q * q, ks = k * k;
  for (int off = 32; off; off >>= 1) {
    qs += __shfl_xor(qs, off);
    ks += __shfl_xor(ks, off);
  }
  q *= rsqrtf(qs * (1.f / 64.f) + EPS_) * qw[d];
  k *= rsqrtf(ks * (1.f / 64.f) + EPS_) * kw[d];
  if (s >= S_ - 1024) {
    int pos = s - (S_ - 1024);
    int i = d >> 1;
    float c = cosT[pos * 32 + i], sn = sinT[pos * 32 + i];
    float qp = __shfl_xor(q, 1), kp = __shfl_xor(k, 1);
    if (d & 1) { q = qp * sn + q * c; k = kp * sn + k * c; }
    else       { q = q * c - qp * sn; k = k * c - kp * sn; }
  }
  q *= 0.125f * 1.44269504088896f;  // fold log2(e): softmax done in base 2
  long o1 = ((long)(bb * NH_ + h) * SP_ + s) * 64 + d;
  qf[o1] = __float2bfloat16(q);
  kf[o1] = __float2bfloat16(k);
}

// swizzled LDS element offset for a [64][8x(8elem)] bf16 tile: row, colchunk cc
#define SWZ(row, cc) (((row) << 6) + ((((cc) ^ ((row) & 7))) << 3))

// ---------------- flash attention: 4 waves/block, 64 q-rows, LDS dbuf K/V ----------------
// UNNORMALIZED softmax: after qk-rmsnorm ||q||=||k||=8 (RoPE is a rotation), so by
// Cauchy-Schwarz |score_base2| <= 8*8*0.125*log2(e) = 11.5 -> exp2 in [2^-11.5, 2^11.5],
// lsum in [0.36, 3.1e6]: no overflow, identical relative error. No max tracking needed.
__global__ __launch_bounds__(256) void attn_k(
    const bf16* __restrict__ qf, const bf16* __restrict__ kf, const bf16* __restrict__ vtf,
    const float* __restrict__ gate, bf16* __restrict__ attn_g) {
  __shared__ __align__(16) bf16 Ks[2][64 * 64];
  __shared__ __align__(16) bf16 Vs[2][64 * 64];
  int bid = blockIdx.x;                      // 1632 = 8 * 204
  int w = (bid & 7) * 204 + (bid >> 3);      // XCD-pinned: 12 bh per XCD
  int bh = w / 17, qb = w - bh * 17;
  int bb = bh / NH_, h = bh - bb * NH_;
  int tid = threadIdx.x;
  int lane = tid & 63, wv = tid >> 6;
  int lr = lane & 15, lg = lane >> 4;
  const bf16* qbase = qf + (long)bh * SP_ * 64;
  const bf16* kbase = kf + (long)bh * SP_ * 64;
  const bf16* vbase = vtf + (long)bh * 64 * SP_;

  int q_l = qb * 64 + wv * 16 + lr;          // q row this lane owns
  bf16x8v qB0 = *(const bf16x8v*)(qbase + (long)q_l * 64 + lg * 8);
  bf16x8v qB1 = *(const bf16x8v*)(qbase + (long)q_l * 64 + 32 + lg * 8);

  f32x4 z; z[0] = z[1] = z[2] = z[3] = 0.f;
  f32x4 acc[4] = {z, z, z, z};
  float tsacc = 0.f;                         // per-lane partial sum (16 of 64 ks per tile)

  auto stage = [&](int buf, int kidx) {
#pragma unroll
    for (int inst = 0; inst < 2; inst++) {
      int c = inst * 256 + tid;
      int row = c >> 3, slot = c & 7;
      int cc = slot ^ (row & 7);
      gload_lds16(kbase + (long)(kidx + row) * 64 + cc * 8, &Ks[buf][c * 8]);
    }
#pragma unroll
    for (int inst = 0; inst < 2; inst++) {
      int c = inst * 256 + tid;
      int row = c >> 3, slot = c & 7;
      int cc = slot ^ (row & 7);
      gload_lds16(vbase + (long)row * SP_ + kidx + cc * 8, &Vs[buf][c * 8]);
    }
  };

  stage(0, 0);
  VMCNT0;
  __syncthreads();
  int cur = 0;

  for (int kt = 0; kt < SP_ / 64; kt++) {
    int kidx = kt * 64;
    if (kt < SP_ / 64 - 1) stage(cur ^ 1, kidx + 64);

    f32x4 p[4];
    __builtin_amdgcn_s_setprio(1);
#pragma unroll
    for (int mt = 0; mt < 4; mt++) {
      int row = mt * 16 + lr;
      bf16x8v k0 = *(const bf16x8v*)&Ks[cur][SWZ(row, lg)];
      bf16x8v k1 = *(const bf16x8v*)&Ks[cur][SWZ(row, lg + 4)];
      f32x4 t = z;
      t = __builtin_amdgcn_mfma_f32_16x16x32_bf16(k0, qB0, t, 0, 0, 0);
      t = __builtin_amdgcn_mfma_f32_16x16x32_bf16(k1, qB1, t, 0, 0, 0);
      p[mt] = t;
    }
    __builtin_amdgcn_s_setprio(0);

    if (kidx + 64 > S_) {
#pragma unroll
      for (int mt = 0; mt < 4; mt++)
#pragma unroll
        for (int r = 0; r < 4; r++)
          if (kidx + mt * 16 + lg * 4 + r >= S_) p[mt][r] = -1e30f;
    }

    // unnormalized: p = exp2(score), accumulate per-lane partial sum
#pragma unroll
    for (int mt = 0; mt < 4; mt++)
#pragma unroll
      for (int r = 0; r < 4; r++) {
        float e = exp2f(p[mt][r]);
        p[mt][r] = e;
        tsacc += e;
      }

    uint32_t w0[4], w1[4];
#pragma unroll
    for (int mt = 0; mt < 4; mt++) {
      asm("v_cvt_pk_bf16_f32 %0, %1, %2" : "=v"(w0[mt]) : "v"(p[mt][0]), "v"(p[mt][1]));
      asm("v_cvt_pk_bf16_f32 %0, %1, %2" : "=v"(w1[mt]) : "v"(p[mt][2]), "v"(p[mt][3]));
    }
    bf16x8v aP[2];
#pragma unroll
    for (int t2 = 0; t2 < 2; t2++) {
      union { uint32_t u[4]; bf16x8v v; } cvt;
#pragma unroll
      for (int wd = 0; wd < 4; wd++) {
        uint32_t a = (wd & 1) ? w1[2 * t2] : w0[2 * t2];
        uint32_t b = (wd & 1) ? w1[2 * t2 + 1] : w0[2 * t2 + 1];
        uint32_t val = (lg & 2) ? b : a;
        int src = ((lg & 1) * 2 + (wd >> 1)) * 16 + lr;
        cvt.u[wd] = (uint32_t)__shfl((int)val, src);
      }
      aP[t2] = cvt.v;
    }
    __builtin_amdgcn_s_setprio(1);
#pragma unroll
    for (int t2 = 0; t2 < 2; t2++)
#pragma unroll
      for (int dt = 0; dt < 4; dt++) {
        int row = dt * 16 + lr;
        bf16x8v vB = *(const bf16x8v*)&Vs[cur][SWZ(row, t2 * 4 + lg)];
        acc[dt] = __builtin_amdgcn_mfma_f32_16x16x32_bf16(aP[t2], vB, acc[dt], 0, 0, 0);
      }
    __builtin_amdgcn_s_setprio(0);

    VMCNT0;
    __syncthreads();
    cur ^= 1;
  }

  // single cross-lane lsum reduce at the end
  tsacc += __shfl_xor(tsacc, 16);
  tsacc += __shfl_xor(tsacc, 32);
  float norm = 0.f;
  if (q_l < S_) norm = gate[((long)bb * S_ + q_l) * 12 + h] / tsacc;
  float nr[4];
#pragma unroll
  for (int r = 0; r < 4; r++) nr[r] = __shfl(norm, lg * 4 + r);
#pragma unroll
  for (int dt = 0; dt < 4; dt++)
#pragma unroll
    for (int r = 0; r < 4; r++) {
      int qr = qb * 64 + wv * 16 + lg * 4 + r;
      if (qr < S_)
        attn_g[((long)bb * S_ + qr) * H_ + h * 64 + dt * 16 + lr] =
            __float2bfloat16(acc[dt][r] * nr[r]);
    }
}

extern "C" void kernel_launch(void* const* d_in, const int* in_sizes, int n_in,
                              void* d_out, int out_size, void* d_ws, size_t ws_size,
                              hipStream_t stream) {
  const float* x    = (const float*)d_in[0];
  const float* cosT = (const float*)d_in[1];
  const float* sinT = (const float*)d_in[2];
  const float* Wq   = (const float*)d_in[3];
  const float* Wk   = (const float*)d_in[4];
  const float* Wv   = (const float*)d_in[5];
  const float* Wo   = (const float*)d_in[6];
  const float* qnw  = (const float*)d_in[7];
  const float* knw  = (const float*)d_in[8];
  const float* gW   = (const float*)d_in[9];
  const float* gb   = (const float*)d_in[10];
  const float* n1w  = (const float*)d_in[11];
  const float* n2w  = (const float*)d_in[12];
  const float* Wg   = (const float*)d_in[13];
  const float* Wu   = (const float*)d_in[14];
  const float* Wd   = (const float*)d_in[15];
  const float* ascale = (const float*)d_in[16];
  const float* mscale = (const float*)d_in[17];

  char* ws = (char*)d_ws;
  size_t off = 0;
  auto alloc = [&](size_t bytes) {
    char* p = ws + off;
    off += (bytes + 255) & ~(size_t)255;
    return p;
  };
  bf16* h_pad  = (bf16*)alloc((size_t)MP_ * H_ * 2);      // reused as h2
  bf16* wqkv_t = (bf16*)alloc((size_t)2304 * 768 * 2);
  bf16* wo_t   = (bf16*)alloc((size_t)768 * 768 * 2);
  bf16* wgu_t  = (bf16*)alloc((size_t)4096 * 768 * 2);    // gate/up 16-col interleaved
  bf16* wdn_t  = (bf16*)alloc((size_t)768 * 2048 * 2);
  bf16* qkv    = (bf16*)alloc((size_t)MP_ * 2304 * 2);    // reused as mlpin (MP_*2048)
  bf16* qfb    = (bf16*)alloc((size_t)96 * SP_ * 64 * 2);
  bf16* kfb    = (bf16*)alloc((size_t)96 * SP_ * 64 * 2);
  bf16* vtfb   = (bf16*)alloc((size_t)96 * SP_ * 64 * 2);
  float* gateb = (float*)alloc((size_t)T_ * 12 * 4);
  bf16* attn_g = (bf16*)alloc((size_t)MP_ * H_ * 2);
  float* x2    = (float*)alloc((size_t)T_ * H_ * 4);
  bf16* mlpin  = qkv;

  // weight conversion
  auto wc = [&](const float* W, bf16* o, int K, int N) {
    wcvt_t<<<dim3(K / 32, N / 32), 256, 0, stream>>>(W, o, K, N);
  };
  wc(Wq, wqkv_t, 768, 768);
  wc(Wk, wqkv_t + 768 * 768, 768, 768);
  wc(Wv, wqkv_t + 2 * 768 * 768, 768, 768);
  wc(Wo, wo_t, 768, 768);
  wc(Wd, wdn_t, 2048, 768);
  wcvt_gu<<<dim3(24, 128), 256, 0, stream>>>(Wg, Wu, wgu_t);

  rmsnorm_k<1><<<MP_, 256, 0, stream>>>(x, n1w, h_pad, gW, gb, gateb, T_);

  // QKV: M=8448 N=2304 K=768
  gemm256<0><<<9 * 33, 512, 0, stream>>>(h_pad, wqkv_t, qkv, 2304, 9);

  qkv_post<<<T_, 768, 0, stream>>>(qkv, qnw, knw, cosT, sinT, qfb, kfb);
  vtran<<<dim3(33, 96), 256, 0, stream>>>(qkv, vtfb);

  attn_k<<<1632, 256, 0, stream>>>(qfb, kfb, vtfb, gateb, attn_g);

  // Wo: fp32 resid+scale epilogue (proven 128^2 GEMM)
  gemm_bf16<1><<<dim3(768 / 128, MP_ / 128), 256, 0, stream>>>(
      attn_g, wo_t, x2, x, ascale, 768, 768, T_);

  rmsnorm_k<0><<<MP_, 256, 0, stream>>>(x2, n2w, h_pad, nullptr, nullptr, nullptr, T_);

  // MLP1: M=8448 N=4096 K=768, silu-fused
  gemm256<2><<<16 * 33, 512, 0, stream>>>(h_pad, wgu_t, mlpin, 4096, 16);

  // MLP2: fp32 resid+scale epilogue (proven 128^2 GEMM)
  gemm_bf16<1><<<dim3(768 / 128, MP_ / 128), 256, 0, stream>>>(
      mlpin, wdn_t, (float*)d_out, x2, mscale, 768, 2048, T_);
}